// Round 2
// baseline (276.596 us; speedup 1.0000x reference)
//
#include <hip/hip_runtime.h>
#include <math.h>

#define B_  2
#define Q_  2048
#define CQ_ 512
#define H_  8
#define D_  64
#define M_  (B_*Q_)   // 4096
#define L2E 1.44269504088896f

typedef __bf16 bf16;
typedef __bf16 bf16x4 __attribute__((ext_vector_type(4)));
typedef __bf16 bf16x8 __attribute__((ext_vector_type(8)));
typedef float  f32x4  __attribute__((ext_vector_type(4)));
typedef float  f32x16 __attribute__((ext_vector_type(16)));
typedef unsigned int u32x2 __attribute__((ext_vector_type(2)));

// async global->LDS, 16 bytes per lane; lds dest = wave-uniform base + lane*16
__device__ __forceinline__ void gl_lds16(const bf16* g, bf16* l) {
    __builtin_amdgcn_global_load_lds(
        (const __attribute__((address_space(1))) unsigned int*)g,
        (__attribute__((address_space(3))) unsigned int*)l, 16, 0, 0);
}

// packed f32x2 -> bf16x2 (RNE), single VOP3
__device__ __forceinline__ unsigned int cvtpk_bf16(float lo, float hi) {
    unsigned int r;
    asm("v_cvt_pk_bf16_f32 %0, %1, %2" : "=v"(r) : "v"(lo), "v"(hi));
    return r;
}

// ---------------------------------------------------------------------------
// fp32 -> bf16 conversion
// ---------------------------------------------------------------------------
#define S0 (4096*512)    // q_x
#define S1 (1536*512)    // w_qkv
#define S2 (512*512)     // w_g
#define S3 (512*512)     // w_o
__global__ __launch_bounds__(256)
void convert_kernel(const float* __restrict__ qx, const float* __restrict__ wqkv,
                    const float* __restrict__ wg, const float* __restrict__ wo,
                    bf16* __restrict__ qxb, bf16* __restrict__ wcat, bf16* __restrict__ wob)
{
    const long long t = (long long)blockIdx.x * 256 + threadIdx.x;
    const long long e = t * 8;
    const float* src; bf16* dst;
    if (e < S0)                { src = qx + e;                  dst = qxb + e; }
    else if (e < S0 + S1)      { src = wqkv + (e - S0);         dst = wcat + (e - S0); }
    else if (e < S0 + S1 + S2) { src = wg + (e - S0 - S1);      dst = wcat + S1 + (e - S0 - S1); }
    else                       { src = wo + (e - S0 - S1 - S2); dst = wob + (e - S0 - S1 - S2); }
    const float4 a = *(const float4*)(src);
    const float4 b = *(const float4*)(src + 4);
    bf16x8 v;
    v[0] = (bf16)a.x; v[1] = (bf16)a.y; v[2] = (bf16)a.z; v[3] = (bf16)a.w;
    v[4] = (bf16)b.x; v[5] = (bf16)b.y; v[6] = (bf16)b.z; v[7] = (bf16)b.w;
    *(bf16x8*)dst = v;
}

// ---------------------------------------------------------------------------
// bf16 MFMA GEMM: C[M,N] = A[M,512] * W[N,512]^T, K=512, BK=32.
// For all parts except V we compute C^T (swapped mfma operands) so each lane
// holds 4 CONSECUTIVE n -> vector stores (b64/b128) instead of 64 scalars.
// EPI 0 (grid.y: 0-3 q, 4-7 k, 8-11 v, 12-15 gate), EPI 1: out = c + b_o.
// K frag order per (b,h), key kk, dim d:
//   off = (kk>>6)*4096 + ((kk>>5)&1)*2048 + (d>>4)*512 + ((d>>3)&1)*256
//       + (kk&31)*8 + (d&7)
// V^T frag order per (b,h):
//   off = (kk>>6)*4096 + (d>>5)*2048 + ((kk&63)>>4)*512 + ((kk>>3)&1)*256
//       + (d&31)*8 + (kk&7)
// ---------------------------------------------------------------------------
template<int BM, int BN, int EPI>
__global__ __launch_bounds__(256)
void gemm_bf16(const bf16* __restrict__ A, const bf16* __restrict__ W,
               const float* __restrict__ bvec, float* __restrict__ fout,
               bf16* __restrict__ qb, bf16* __restrict__ kb, bf16* __restrict__ vb,
               bf16* __restrict__ gb)
{
    constexpr int MI = BM / 32, NJ = BN / 32;
    __shared__ __align__(16) bf16 As[BM * 32];
    __shared__ __align__(16) bf16 Bs[BN * 32];

    const int t = threadIdx.x;
    const int w = t >> 6, lane = t & 63;
    const int l15 = lane & 15, quad = lane >> 4;
    const int wm = w & 1, wn = w >> 1;
    const int bm = blockIdx.x * BM;
    const int bn = blockIdx.y * BN;
    const bool swapped = (EPI == 1) || ((bn >> 9) != 2);

    f32x4 acc[MI][NJ] = {};

    const int rr = t >> 2;
    const int cc = (t & 3) * 8;

    for (int k0 = 0; k0 < 512; k0 += 32) {
        #pragma unroll
        for (int i = 0; i < BM / 64; ++i)
            gl_lds16(A + (size_t)(bm + i * 64 + rr) * 512 + k0 + cc,
                     As + (i * 64 + w * 16) * 32);
        #pragma unroll
        for (int i = 0; i < BN / 64; ++i)
            gl_lds16(W + (size_t)(bn + i * 64 + rr) * 512 + k0 + cc,
                     Bs + (i * 64 + w * 16) * 32);
        __asm__ volatile("s_waitcnt vmcnt(0)" ::: "memory");
        __syncthreads();

        bf16x8 af[MI], bfr[NJ];
        #pragma unroll
        for (int i = 0; i < MI; ++i)
            af[i] = *(const bf16x8*)(As + (wm * (BM / 2) + i * 16 + l15) * 32 + quad * 8);
        #pragma unroll
        for (int j = 0; j < NJ; ++j)
            bfr[j] = *(const bf16x8*)(Bs + (wn * (BN / 2) + j * 16 + l15) * 32 + quad * 8);
        if (swapped) {
            #pragma unroll
            for (int i = 0; i < MI; ++i)
                #pragma unroll
                for (int j = 0; j < NJ; ++j)
                    acc[i][j] = __builtin_amdgcn_mfma_f32_16x16x32_bf16(bfr[j], af[i], acc[i][j], 0, 0, 0);
        } else {
            #pragma unroll
            for (int i = 0; i < MI; ++i)
                #pragma unroll
                for (int j = 0; j < NJ; ++j)
                    acc[i][j] = __builtin_amdgcn_mfma_f32_16x16x32_bf16(af[i], bfr[j], acc[i][j], 0, 0, 0);
        }
        __syncthreads();
    }

    if (swapped) {
        #pragma unroll
        for (int i = 0; i < MI; ++i) {
            const int m = bm + wm * (BM / 2) + i * 16 + l15;
            const int b = m >> 11, qq = m & 2047;
            #pragma unroll
            for (int j = 0; j < NJ; ++j) {
                const int n0 = bn + wn * (BN / 2) + j * 16 + quad * 4;
                const f32x4 cv = acc[i][j];
                if constexpr (EPI == 1) {
                    float4 st;
                    st.x = cv[0] + bvec[n0 + 0];
                    st.y = cv[1] + bvec[n0 + 1];
                    st.z = cv[2] + bvec[n0 + 2];
                    st.w = cv[3] + bvec[n0 + 3];
                    *(float4*)(fout + (size_t)m * 512 + n0) = st;
                } else {
                    const int part = n0 >> 9;
                    if (part == 0) {
                        const int h = (n0 >> 6) & 7, d0 = n0 & 63;
                        bf16x4 q4;
                        #pragma unroll
                        for (int r = 0; r < 4; ++r) q4[r] = (bf16)(cv[r] * (0.125f * L2E));
                        *(bf16x4*)(qb + (size_t)(b * H_ + h) * (Q_ * D_) + (size_t)qq * 64 + d0) = q4;
                    } else if (part == 1) {
                        const int h = (n0 >> 6) & 7, d0 = n0 & 63;
                        const size_t off = (size_t)(b * H_ + h) * (Q_ * D_)
                            + (qq >> 6) * 4096 + ((qq >> 5) & 1) * 2048
                            + (d0 >> 4) * 512 + ((d0 >> 3) & 1) * 256
                            + (qq & 31) * 8 + (d0 & 7);
                        bf16x4 k4;
                        #pragma unroll
                        for (int r = 0; r < 4; ++r) k4[r] = (bf16)cv[r];
                        *(bf16x4*)(kb + off) = k4;
                    } else {
                        const int gcol = n0 & 511;
                        const float4 bv4 = *(const float4*)(bvec + gcol);
                        bf16x4 g4;
                        g4[0] = (bf16)(1.f / (1.f + __expf(-(cv[0] + bv4.x))));
                        g4[1] = (bf16)(1.f / (1.f + __expf(-(cv[1] + bv4.y))));
                        g4[2] = (bf16)(1.f / (1.f + __expf(-(cv[2] + bv4.z))));
                        g4[3] = (bf16)(1.f / (1.f + __expf(-(cv[3] + bv4.w))));
                        *(bf16x4*)(gb + (size_t)m * 512 + gcol) = g4;
                    }
                }
            }
        }
    } else {
        // V part, normal orientation: lane holds 4 consecutive qq for fixed d
        #pragma unroll
        for (int i = 0; i < MI; ++i) {
            const int m0 = bm + wm * (BM / 2) + i * 16 + quad * 4;
            const int b = m0 >> 11, qq0 = m0 & 2047;
            #pragma unroll
            for (int j = 0; j < NJ; ++j) {
                const int n = bn + wn * (BN / 2) + j * 16 + l15;
                const int h = (n >> 6) & 7, d = n & 63;
                const size_t off = (size_t)(b * H_ + h) * (Q_ * D_)
                    + (qq0 >> 6) * 4096 + (d >> 5) * 2048
                    + ((qq0 & 63) >> 4) * 512 + ((qq0 >> 3) & 1) * 256
                    + (d & 31) * 8 + (qq0 & 7);
                bf16x4 v4;
                #pragma unroll
                for (int r = 0; r < 4; ++r) v4[r] = (bf16)acc[i][j][r];
                *(bf16x4*)(vb + off) = v4;
            }
        }
    }
}

// ---------------------------------------------------------------------------
// Split-K MFMA flash attention (32x32x16, transposed dataflow S^T/O^T).
// Grid (16 bh, 16 qt, 4 ks) = 1024 blocks -> 4 blocks/CU co-resident.
// Block = 4 waves x 32 q-rows = 128 q; key slab = ks*512..+512, 8 steps.
// K/V LDS-staged in fragment order via global_load_lds (conflict-free),
// double-buffered, one barrier/step. P transpose done IN-REGISTER via
// v_cvt_pk_bf16_f32 + permlane32_swap (T12): no Ps LDS, no lgkmcnt stall.
// permlane32_swap(a,b): ret[0] = {a_low | b_low->hi lanes},
//                       ret[1] = {a_high->lo lanes | b_high}  (ISA-verified dir)
// LDS = 32 KiB/block -> 4 blocks/CU. Partial out: normalized O (bf16) + m,l.
// ---------------------------------------------------------------------------
__global__ __launch_bounds__(256, 4)
void attn_part(const bf16* __restrict__ qb, const bf16* __restrict__ kf,
               const bf16* __restrict__ vf, const float* __restrict__ bias,
               bf16* __restrict__ po, float2* __restrict__ ml)
{
    __shared__ __align__(16) bf16 Ks[2][4096];
    __shared__ __align__(16) bf16 Vs[2][4096];

    const int tid  = threadIdx.x;
    const int wv   = tid >> 6, lane = tid & 63;
    const int l31  = lane & 31, b5 = lane >> 5;
    const int x    = blockIdx.x;
    const int bh   = ((x & 7) << 1) | (x >> 3);   // XCD gets same-b head pair
    const int b    = bh >> 3;
    const int qg   = blockIdx.y * 128 + wv * 32 + l31;
    const int ks   = blockIdx.z;

    const bf16* qp = qb + ((size_t)bh * Q_ + qg) * D_;
    bf16x8 bq[4];
    #pragma unroll
    for (int c = 0; c < 4; ++c)
        bq[c] = *(const bf16x8*)(qp + c * 16 + b5 * 8);

    f32x16 acc[2] = {};
    float m_run = -INFINITY, l_run = 0.f;

    const bf16*  kfb  = kf + (size_t)bh * (Q_ * D_) + (size_t)ks * 8 * 4096;
    const bf16*  vfb  = vf + (size_t)bh * (Q_ * D_) + (size_t)ks * 8 * 4096;
    const float* brow = bias + ((size_t)b * Q_ + qg) * Q_ + ks * 512;

    f32x4 bcur[8], bnxt[8];

    #pragma unroll
    for (int p = 0; p < 2; ++p) {
        gl_lds16(kfb + (wv * 2 + p) * 512 + lane * 8, Ks[0] + (wv * 2 + p) * 512);
        gl_lds16(vfb + (wv * 2 + p) * 512 + lane * 8, Vs[0] + (wv * 2 + p) * 512);
    }
    #pragma unroll
    for (int i = 0; i < 8; ++i)
        bcur[i] = *(const f32x4*)(brow + (i >> 2) * 32 + (i & 3) * 8 + b5 * 4);
    __asm__ volatile("s_waitcnt vmcnt(0)" ::: "memory");
    __syncthreads();

    int cur = 0;
    #pragma unroll 1
    for (int t = 0; t < 8; ++t) {
        if (t < 7) {
            const size_t off = (size_t)(t + 1) * 4096;
            #pragma unroll
            for (int p = 0; p < 2; ++p) {
                gl_lds16(kfb + off + (wv * 2 + p) * 512 + lane * 8,
                         Ks[cur ^ 1] + (wv * 2 + p) * 512);
                gl_lds16(vfb + off + (wv * 2 + p) * 512 + lane * 8,
                         Vs[cur ^ 1] + (wv * 2 + p) * 512);
            }
            const int k0n = (t + 1) * 64;
            #pragma unroll
            for (int i = 0; i < 8; ++i)
                bnxt[i] = *(const f32x4*)(brow + k0n + (i >> 2) * 32 + (i & 3) * 8 + b5 * 4);
        }

        const bf16* Kc = Ks[cur];
        f32x16 sv[2] = {};
        __builtin_amdgcn_s_setprio(1);
        #pragma unroll
        for (int kg = 0; kg < 2; ++kg)
            #pragma unroll
            for (int c = 0; c < 4; ++c) {
                const bf16x8 ak = *(const bf16x8*)(Kc + kg * 2048 + c * 512 + lane * 8);
                sv[kg] = __builtin_amdgcn_mfma_f32_32x32x16_bf16(ak, bq[c], sv[kg], 0, 0, 0);
            }
        __builtin_amdgcn_s_setprio(0);

        float sc[2][16];
        #pragma unroll
        for (int kg = 0; kg < 2; ++kg)
            #pragma unroll
            for (int r = 0; r < 16; ++r)
                sc[kg][r] = fmaf(bcur[kg * 4 + (r >> 2)][r & 3], L2E, sv[kg][r]);

        // tree max (depth ~5 instead of serial-31)
        float mx[16];
        #pragma unroll
        for (int r = 0; r < 16; ++r) mx[r] = fmaxf(sc[0][r], sc[1][r]);
        #pragma unroll
        for (int r = 0; r < 8; ++r) mx[r] = fmaxf(mx[r], mx[r + 8]);
        #pragma unroll
        for (int r = 0; r < 4; ++r) mx[r] = fmaxf(mx[r], mx[r + 4]);
        float tmax = fmaxf(fmaxf(mx[0], mx[1]), fmaxf(mx[2], mx[3]));
        tmax = fmaxf(tmax, __shfl_xor(tmax, 32, 64));

        const float mn = fmaxf(m_run, tmax);
        const float alpha = __builtin_amdgcn_exp2f(m_run - mn);
        m_run = mn;

        #pragma unroll
        for (int kg = 0; kg < 2; ++kg)
            #pragma unroll
            for (int r = 0; r < 16; ++r)
                sc[kg][r] = __builtin_amdgcn_exp2f(sc[kg][r] - mn);

        // tree sum
        float sm[16];
        #pragma unroll
        for (int r = 0; r < 16; ++r) sm[r] = sc[0][r] + sc[1][r];
        #pragma unroll
        for (int r = 0; r < 8; ++r) sm[r] += sm[r + 8];
        #pragma unroll
        for (int r = 0; r < 4; ++r) sm[r] += sm[r + 4];
        float rsum = (sm[0] + sm[1]) + (sm[2] + sm[3]);
        rsum += __shfl_xor(rsum, 32, 64);
        l_run = l_run * alpha + rsum;
        acc[0] *= alpha;
        acc[1] *= alpha;

        // ---- T12: in-register P -> B-operand fragments ----
        // lane holds sc[kg][g*4+q] = P[kk = kg*32 + 8g + 4*b5 + q][q-col=l31].
        // B-frag for 16-k chunk (kg,h), dest lane (b5,l31) needs
        //   bp[j] = P[kg*32 + 16h + 8*b5 + j][l31], i.e. src gi = 2h + b5dst:
        //   dword0 = {u_low | vv_low}   dword2 = {u_high | vv_high}
        // with u = pk(gi=2h, q=0,1), vv = pk(gi=2h+1, q=0,1). These are exactly
        // permlane32_swap(u, vv)[0] and [1].
        bf16x8 bp[4];
        #pragma unroll
        for (int kg = 0; kg < 2; ++kg)
            #pragma unroll
            for (int h = 0; h < 2; ++h) {
                const unsigned int u  = cvtpk_bf16(sc[kg][8 * h + 0], sc[kg][8 * h + 1]);
                const unsigned int u2 = cvtpk_bf16(sc[kg][8 * h + 2], sc[kg][8 * h + 3]);
                const unsigned int vv = cvtpk_bf16(sc[kg][8 * h + 4], sc[kg][8 * h + 5]);
                const unsigned int v2 = cvtpk_bf16(sc[kg][8 * h + 6], sc[kg][8 * h + 7]);
                const u32x2 s1 = __builtin_amdgcn_permlane32_swap(u,  vv, false, false);
                const u32x2 s2 = __builtin_amdgcn_permlane32_swap(u2, v2, false, false);
                union { unsigned int w[4]; bf16x8 v8; } pkw;
                pkw.w[0] = s1[0]; pkw.w[1] = s2[0]; pkw.w[2] = s1[1]; pkw.w[3] = s2[1];
                bp[kg * 2 + h] = pkw.v8;
            }

        const bf16* Vc = Vs[cur];
        __builtin_amdgcn_s_setprio(1);
        #pragma unroll
        for (int c4 = 0; c4 < 4; ++c4) {
            #pragma unroll
            for (int dg = 0; dg < 2; ++dg) {
                const bf16x8 av = *(const bf16x8*)(Vc + dg * 2048 + c4 * 512 + lane * 8);
                acc[dg] = __builtin_amdgcn_mfma_f32_32x32x16_bf16(av, bp[c4], acc[dg], 0, 0, 0);
            }
        }
        __builtin_amdgcn_s_setprio(0);

        if (t < 7) {
            #pragma unroll
            for (int i = 0; i < 8; ++i) bcur[i] = bnxt[i];
        }
        __asm__ volatile("s_waitcnt vmcnt(0)" ::: "memory");
        __syncthreads();
        cur ^= 1;
    }

    // ---- partial epilogue: normalized O (bf16) + (m, l) ----
    const float inv = 1.f / l_run;
    const size_t pbase = ((size_t)(ks * 16 + bh) * Q_ + qg) * 64;
    #pragma unroll
    for (int dg = 0; dg < 2; ++dg)
        #pragma unroll
        for (int gi = 0; gi < 4; ++gi) {
            const int d0 = dg * 32 + gi * 8 + b5 * 4;
            bf16x4 ov;
            #pragma unroll
            for (int r = 0; r < 4; ++r)
                ov[r] = (bf16)(acc[dg][gi * 4 + r] * inv);
            *(bf16x4*)(po + pbase + d0) = ov;
        }
    if (b5 == 0)
        ml[(size_t)(ks * 16 + bh) * Q_ + qg] = make_float2(m_run, l_run);
}

// ---------------------------------------------------------------------------
// Merge 4 split-K partials, apply gate, write bf16 [M,512].
// ---------------------------------------------------------------------------
__global__ __launch_bounds__(256)
void merge_kernel(const bf16* __restrict__ po, const float2* __restrict__ ml,
                  const bf16* __restrict__ g, bf16* __restrict__ og)
{
    const int gid = blockIdx.x * 256 + threadIdx.x;
    const int row = gid >> 3;             // bh*2048 + qg
    const int d8  = (gid & 7) * 8;
    const int bh  = row >> 11, qg = row & 2047;
    const int b   = bh >> 3, h = bh & 7;

    float2 m4[4];
    #pragma unroll
    for (int s = 0; s < 4; ++s) m4[s] = ml[(size_t)s * (16 * Q_) + row];
    const float M = fmaxf(fmaxf(m4[0].x, m4[1].x), fmaxf(m4[2].x, m4[3].x));
    float w[4], tot = 0.f;
    #pragma unroll
    for (int s = 0; s < 4; ++s) {
        w[s] = m4[s].y * __builtin_amdgcn_exp2f(m4[s].x - M);
        tot += w[s];
    }
    const float inv = 1.f / tot;
    #pragma unroll
    for (int s = 0; s < 4; ++s) w[s] *= inv;

    bf16x8 o[4];
    #pragma unroll
    for (int s = 0; s < 4; ++s)
        o[s] = *(const bf16x8*)(po + (size_t)s * (16 * Q_ * 64) + (size_t)row * 64 + d8);

    const size_t obase = ((size_t)(b * Q_ + qg)) * 512 + h * 64 + d8;
    const bf16x8 gv = *(const bf16x8*)(g + obase);
    bf16x8 ov;
    #pragma unroll
    for (int r = 0; r < 8; ++r) {
        float acc = 0.f;
        #pragma unroll
        for (int s = 0; s < 4; ++s) acc += (float)o[s][r] * w[s];
        ov[r] = (bf16)(acc * (float)gv[r]);
    }
    *(bf16x8*)(og + obase) = ov;
}

// ---------------------------------------------------------------------------
extern "C" void kernel_launch(void* const* d_in, const int* in_sizes, int n_in,
                              void* d_out, int out_size, void* d_ws, size_t ws_size,
                              hipStream_t stream)
{
    const float* q_x   = (const float*)d_in[0];
    const float* bias  = (const float*)d_in[2];
    const float* w_qkv = (const float*)d_in[3];
    const float* w_o   = (const float*)d_in[4];
    const float* b_o   = (const float*)d_in[5];
    const float* w_g   = (const float*)d_in[6];
    const float* b_g   = (const float*)d_in[7];
    float* out = (float*)d_out;

    char* ws = (char*)d_ws;
    bf16*   qxb  = (bf16*)(ws);                    // 4 MB  (dead after gemm0)
    bf16*   wcat = (bf16*)(ws + (4u  << 20));      // 2 MB  (dead after gemm0)
    bf16*   po   = (bf16*)(ws);                    // 16 MB partials (overlays qxb/wcat)
    bf16*   qb   = (bf16*)(ws + (16u << 20));      // 4 MB
    bf16*   kb   = (bf16*)(ws + (20u << 20));      // 4 MB  K frag-ordered
    bf16*   vb   = (bf16*)(ws + (24u << 20));      // 4 MB  V^T frag-ordered
    bf16*   gb   = (bf16*)(ws + (28u << 20));      // 4 MB  gate
    bf16*   ogb  = (bf16*)(ws + (32u << 20));      // 4 MB  gated O
    bf16*   wob  = (bf16*)(ws + (36u << 20));      // 0.5 MB
    float2* ml   = (float2*)(ws + (36u << 20) + (1u << 19));  // 1 MB -> ends 37.5 MB

    // 1) fp32 -> bf16 conversions
    convert_kernel<<<(S0 + S1 + S2 + S3) / (256 * 8), 256, 0, stream>>>(
        q_x, w_qkv, w_g, w_o, qxb, wcat, wob);
    // 2) fused QKV + gate projection (bf16 MFMA, coalesced epilogue)
    gemm_bf16<128, 128, 0><<<dim3(32, 16), 256, 0, stream>>>(
        qxb, wcat, b_g, nullptr, qb, kb, vb, gb);
    // 3) split-K flash attention partials (4-way split, 4 blocks/CU)
    attn_part<<<dim3(B_ * H_, Q_ / 128, 4), 256, 0, stream>>>(qb, kb, vb, bias, po, ml);
    // 4) merge partials + gate
    merge_kernel<<<(16 * Q_ * 8) / 256, 256, 0, stream>>>(po, ml, gb, ogb);
    // 5) output projection + b_o
    gemm_bf16<64, 128, 1><<<dim3(64, 4), 256, 0, stream>>>(
        ogb, wob, b_o, out, nullptr, nullptr, nullptr, nullptr);
}

// Round 3
// 196.813 us; speedup vs baseline: 1.4054x; 1.4054x over previous
//
#include <hip/hip_runtime.h>
#include <math.h>

#define B_  2
#define Q_  2048
#define CQ_ 512
#define H_  8
#define D_  64
#define M_  (B_*Q_)   // 4096
#define L2E 1.44269504088896f

typedef __bf16 bf16;
typedef __bf16 bf16x4 __attribute__((ext_vector_type(4)));
typedef __bf16 bf16x8 __attribute__((ext_vector_type(8)));
typedef float  f32x4  __attribute__((ext_vector_type(4)));
typedef float  f32x16 __attribute__((ext_vector_type(16)));
typedef unsigned int u32x2 __attribute__((ext_vector_type(2)));

// async global->LDS, 16 bytes per lane; lds dest = wave-uniform base + lane*16
__device__ __forceinline__ void gl_lds16(const bf16* g, bf16* l) {
    __builtin_amdgcn_global_load_lds(
        (const __attribute__((address_space(1))) unsigned int*)g,
        (__attribute__((address_space(3))) unsigned int*)l, 16, 0, 0);
}

// packed f32x2 -> bf16x2 (RNE), single VOP3
__device__ __forceinline__ unsigned int cvtpk_bf16(float lo, float hi) {
    unsigned int r;
    asm("v_cvt_pk_bf16_f32 %0, %1, %2" : "=v"(r) : "v"(lo), "v"(hi));
    return r;
}

// ---------------------------------------------------------------------------
// fp32 -> bf16 conversion
// ---------------------------------------------------------------------------
#define S0 (4096*512)    // q_x
#define S1 (1536*512)    // w_qkv
#define S2 (512*512)     // w_g
#define S3 (512*512)     // w_o
__global__ __launch_bounds__(256)
void convert_kernel(const float* __restrict__ qx, const float* __restrict__ wqkv,
                    const float* __restrict__ wg, const float* __restrict__ wo,
                    bf16* __restrict__ qxb, bf16* __restrict__ wcat, bf16* __restrict__ wob)
{
    const long long t = (long long)blockIdx.x * 256 + threadIdx.x;
    const long long e = t * 8;
    const float* src; bf16* dst;
    if (e < S0)                { src = qx + e;                  dst = qxb + e; }
    else if (e < S0 + S1)      { src = wqkv + (e - S0);         dst = wcat + (e - S0); }
    else if (e < S0 + S1 + S2) { src = wg + (e - S0 - S1);      dst = wcat + S1 + (e - S0 - S1); }
    else                       { src = wo + (e - S0 - S1 - S2); dst = wob + (e - S0 - S1 - S2); }
    const float4 a = *(const float4*)(src);
    const float4 b = *(const float4*)(src + 4);
    bf16x8 v;
    v[0] = (bf16)a.x; v[1] = (bf16)a.y; v[2] = (bf16)a.z; v[3] = (bf16)a.w;
    v[4] = (bf16)b.x; v[5] = (bf16)b.y; v[6] = (bf16)b.z; v[7] = (bf16)b.w;
    *(bf16x8*)dst = v;
}

// ---------------------------------------------------------------------------
// bf16 MFMA GEMM: C[M,N] = A[M,512] * W[N,512]^T, K=512, BK=32.
// For all parts except V we compute C^T (swapped mfma operands) so each lane
// holds 4 CONSECUTIVE n -> vector stores (b64/b128) instead of 64 scalars.
// EPI 0 (grid.y: 0-3 q, 4-7 k, 8-11 v, 12-15 gate), EPI 1: out = c + b_o.
// K frag order per (b,h), key kk, dim d:
//   off = (kk>>6)*4096 + ((kk>>5)&1)*2048 + (d>>4)*512 + ((d>>3)&1)*256
//       + (kk&31)*8 + (d&7)
// V^T frag order per (b,h):
//   off = (kk>>6)*4096 + (d>>5)*2048 + ((kk&63)>>4)*512 + ((kk>>3)&1)*256
//       + (d&31)*8 + (kk&7)
// ---------------------------------------------------------------------------
template<int BM, int BN, int EPI>
__global__ __launch_bounds__(256)
void gemm_bf16(const bf16* __restrict__ A, const bf16* __restrict__ W,
               const float* __restrict__ bvec, float* __restrict__ fout,
               bf16* __restrict__ qb, bf16* __restrict__ kb, bf16* __restrict__ vb,
               bf16* __restrict__ gb)
{
    constexpr int MI = BM / 32, NJ = BN / 32;
    __shared__ __align__(16) bf16 As[BM * 32];
    __shared__ __align__(16) bf16 Bs[BN * 32];

    const int t = threadIdx.x;
    const int w = t >> 6, lane = t & 63;
    const int l15 = lane & 15, quad = lane >> 4;
    const int wm = w & 1, wn = w >> 1;
    const int bm = blockIdx.x * BM;
    const int bn = blockIdx.y * BN;
    const bool swapped = (EPI == 1) || ((bn >> 9) != 2);

    f32x4 acc[MI][NJ] = {};

    const int rr = t >> 2;
    const int cc = (t & 3) * 8;

    for (int k0 = 0; k0 < 512; k0 += 32) {
        #pragma unroll
        for (int i = 0; i < BM / 64; ++i)
            gl_lds16(A + (size_t)(bm + i * 64 + rr) * 512 + k0 + cc,
                     As + (i * 64 + w * 16) * 32);
        #pragma unroll
        for (int i = 0; i < BN / 64; ++i)
            gl_lds16(W + (size_t)(bn + i * 64 + rr) * 512 + k0 + cc,
                     Bs + (i * 64 + w * 16) * 32);
        __asm__ volatile("s_waitcnt vmcnt(0)" ::: "memory");
        __syncthreads();

        bf16x8 af[MI], bfr[NJ];
        #pragma unroll
        for (int i = 0; i < MI; ++i)
            af[i] = *(const bf16x8*)(As + (wm * (BM / 2) + i * 16 + l15) * 32 + quad * 8);
        #pragma unroll
        for (int j = 0; j < NJ; ++j)
            bfr[j] = *(const bf16x8*)(Bs + (wn * (BN / 2) + j * 16 + l15) * 32 + quad * 8);
        if (swapped) {
            #pragma unroll
            for (int i = 0; i < MI; ++i)
                #pragma unroll
                for (int j = 0; j < NJ; ++j)
                    acc[i][j] = __builtin_amdgcn_mfma_f32_16x16x32_bf16(bfr[j], af[i], acc[i][j], 0, 0, 0);
        } else {
            #pragma unroll
            for (int i = 0; i < MI; ++i)
                #pragma unroll
                for (int j = 0; j < NJ; ++j)
                    acc[i][j] = __builtin_amdgcn_mfma_f32_16x16x32_bf16(af[i], bfr[j], acc[i][j], 0, 0, 0);
        }
        __syncthreads();
    }

    if (swapped) {
        #pragma unroll
        for (int i = 0; i < MI; ++i) {
            const int m = bm + wm * (BM / 2) + i * 16 + l15;
            const int b = m >> 11, qq = m & 2047;
            #pragma unroll
            for (int j = 0; j < NJ; ++j) {
                const int n0 = bn + wn * (BN / 2) + j * 16 + quad * 4;
                const f32x4 cv = acc[i][j];
                if constexpr (EPI == 1) {
                    float4 st;
                    st.x = cv[0] + bvec[n0 + 0];
                    st.y = cv[1] + bvec[n0 + 1];
                    st.z = cv[2] + bvec[n0 + 2];
                    st.w = cv[3] + bvec[n0 + 3];
                    *(float4*)(fout + (size_t)m * 512 + n0) = st;
                } else {
                    const int part = n0 >> 9;
                    if (part == 0) {
                        const int h = (n0 >> 6) & 7, d0 = n0 & 63;
                        bf16x4 q4;
                        #pragma unroll
                        for (int r = 0; r < 4; ++r) q4[r] = (bf16)(cv[r] * (0.125f * L2E));
                        *(bf16x4*)(qb + (size_t)(b * H_ + h) * (Q_ * D_) + (size_t)qq * 64 + d0) = q4;
                    } else if (part == 1) {
                        const int h = (n0 >> 6) & 7, d0 = n0 & 63;
                        const size_t off = (size_t)(b * H_ + h) * (Q_ * D_)
                            + (qq >> 6) * 4096 + ((qq >> 5) & 1) * 2048
                            + (d0 >> 4) * 512 + ((d0 >> 3) & 1) * 256
                            + (qq & 31) * 8 + (d0 & 7);
                        bf16x4 k4;
                        #pragma unroll
                        for (int r = 0; r < 4; ++r) k4[r] = (bf16)cv[r];
                        *(bf16x4*)(kb + off) = k4;
                    } else {
                        const int gcol = n0 & 511;
                        const float4 bv4 = *(const float4*)(bvec + gcol);
                        bf16x4 g4;
                        g4[0] = (bf16)(1.f / (1.f + __expf(-(cv[0] + bv4.x))));
                        g4[1] = (bf16)(1.f / (1.f + __expf(-(cv[1] + bv4.y))));
                        g4[2] = (bf16)(1.f / (1.f + __expf(-(cv[2] + bv4.z))));
                        g4[3] = (bf16)(1.f / (1.f + __expf(-(cv[3] + bv4.w))));
                        *(bf16x4*)(gb + (size_t)m * 512 + gcol) = g4;
                    }
                }
            }
        }
    } else {
        // V part, normal orientation: lane holds 4 consecutive qq for fixed d
        #pragma unroll
        for (int i = 0; i < MI; ++i) {
            const int m0 = bm + wm * (BM / 2) + i * 16 + quad * 4;
            const int b = m0 >> 11, qq0 = m0 & 2047;
            #pragma unroll
            for (int j = 0; j < NJ; ++j) {
                const int n = bn + wn * (BN / 2) + j * 16 + l15;
                const int h = (n >> 6) & 7, d = n & 63;
                const size_t off = (size_t)(b * H_ + h) * (Q_ * D_)
                    + (qq0 >> 6) * 4096 + (d >> 5) * 2048
                    + ((qq0 & 63) >> 4) * 512 + ((qq0 >> 3) & 1) * 256
                    + (d & 31) * 8 + (qq0 & 7);
                bf16x4 v4;
                #pragma unroll
                for (int r = 0; r < 4; ++r) v4[r] = (bf16)acc[i][j][r];
                *(bf16x4*)(vb + off) = v4;
            }
        }
    }
}

// ---------------------------------------------------------------------------
// Split-K MFMA flash attention (32x32x16, transposed dataflow S^T/O^T).
// Grid (16 bh, 16 qt, 4 ks) = 1024 blocks -> 4 blocks/CU co-resident.
// Block = 4 waves x 32 q-rows = 128 q; key slab = ks*512..+512, 8 steps.
// K/V LDS-staged in fragment order via global_load_lds (conflict-free),
// double-buffered, one barrier/step. P transpose IN-REGISTER via
// v_cvt_pk_bf16_f32 + permlane32_swap (T12).
// Register discipline (fit 128 VGPR, no spill):
//  - bias enters QK^T as the MFMA C-in (sv init = bias*L2E) -> bias regs die
//    at step start instead of after the MFMA cluster.
//  - single nb[8] bias set, refilled during PV phase (after sc dies); no
//    bcur/bnxt copy, lifetimes never overlap.
// LDS = 32 KiB/block -> 4 blocks/CU. Partial out: normalized O (bf16) + m,l.
// ---------------------------------------------------------------------------
__global__ __launch_bounds__(256, 4)
void attn_part(const bf16* __restrict__ qb, const bf16* __restrict__ kf,
               const bf16* __restrict__ vf, const float* __restrict__ bias,
               bf16* __restrict__ po, float2* __restrict__ ml)
{
    __shared__ __align__(16) bf16 Ks[2][4096];
    __shared__ __align__(16) bf16 Vs[2][4096];

    const int tid  = threadIdx.x;
    const int wv   = tid >> 6, lane = tid & 63;
    const int l31  = lane & 31, b5 = lane >> 5;
    const int x    = blockIdx.x;
    const int bh   = ((x & 7) << 1) | (x >> 3);   // XCD gets same-b head pair
    const int b    = bh >> 3;
    const int qg   = blockIdx.y * 128 + wv * 32 + l31;
    const int ks   = blockIdx.z;

    const bf16* qp = qb + ((size_t)bh * Q_ + qg) * D_;
    bf16x8 bq[4];
    #pragma unroll
    for (int c = 0; c < 4; ++c)
        bq[c] = *(const bf16x8*)(qp + c * 16 + b5 * 8);

    f32x16 acc[2] = {};
    float m_run = -INFINITY, l_run = 0.f;

    const bf16*  kfb  = kf + (size_t)bh * (Q_ * D_) + (size_t)ks * 8 * 4096;
    const bf16*  vfb  = vf + (size_t)bh * (Q_ * D_) + (size_t)ks * 8 * 4096;
    const float* brow = bias + ((size_t)b * Q_ + qg) * Q_ + ks * 512;

    f32x4 nb[8];

    #pragma unroll
    for (int p = 0; p < 2; ++p) {
        gl_lds16(kfb + (wv * 2 + p) * 512 + lane * 8, Ks[0] + (wv * 2 + p) * 512);
        gl_lds16(vfb + (wv * 2 + p) * 512 + lane * 8, Vs[0] + (wv * 2 + p) * 512);
    }
    #pragma unroll
    for (int i = 0; i < 8; ++i)
        nb[i] = *(const f32x4*)(brow + (i >> 2) * 32 + (i & 3) * 8 + b5 * 4);
    __asm__ volatile("s_waitcnt vmcnt(0)" ::: "memory");
    __syncthreads();

    int cur = 0;
    #pragma unroll 1
    for (int t = 0; t < 8; ++t) {
        // K/V prefetch for next step (no VGPR cost: direct-to-LDS)
        if (t < 7) {
            const size_t off = (size_t)(t + 1) * 4096;
            #pragma unroll
            for (int p = 0; p < 2; ++p) {
                gl_lds16(kfb + off + (wv * 2 + p) * 512 + lane * 8,
                         Ks[cur ^ 1] + (wv * 2 + p) * 512);
                gl_lds16(vfb + off + (wv * 2 + p) * 512 + lane * 8,
                         Vs[cur ^ 1] + (wv * 2 + p) * 512);
            }
        }

        // sv init = bias*L2E (MFMA C-in); nb dies here
        f32x16 sv[2];
        #pragma unroll
        for (int kg = 0; kg < 2; ++kg)
            #pragma unroll
            for (int r = 0; r < 16; ++r)
                sv[kg][r] = nb[kg * 4 + (r >> 2)][r & 3] * L2E;

        const bf16* Kc = Ks[cur];
        __builtin_amdgcn_s_setprio(1);
        #pragma unroll
        for (int kg = 0; kg < 2; ++kg)
            #pragma unroll
            for (int c = 0; c < 4; ++c) {
                const bf16x8 ak = *(const bf16x8*)(Kc + kg * 2048 + c * 512 + lane * 8);
                sv[kg] = __builtin_amdgcn_mfma_f32_32x32x16_bf16(ak, bq[c], sv[kg], 0, 0, 0);
            }
        __builtin_amdgcn_s_setprio(0);

        // tree max (depth ~5)
        float mx[16];
        #pragma unroll
        for (int r = 0; r < 16; ++r) mx[r] = fmaxf(sv[0][r], sv[1][r]);
        #pragma unroll
        for (int r = 0; r < 8; ++r) mx[r] = fmaxf(mx[r], mx[r + 8]);
        #pragma unroll
        for (int r = 0; r < 4; ++r) mx[r] = fmaxf(mx[r], mx[r + 4]);
        float tmax = fmaxf(fmaxf(mx[0], mx[1]), fmaxf(mx[2], mx[3]));
        tmax = fmaxf(tmax, __shfl_xor(tmax, 32, 64));

        const float mn = fmaxf(m_run, tmax);
        const float alpha = __builtin_amdgcn_exp2f(m_run - mn);
        m_run = mn;

        #pragma unroll
        for (int kg = 0; kg < 2; ++kg)
            #pragma unroll
            for (int r = 0; r < 16; ++r)
                sv[kg][r] = __builtin_amdgcn_exp2f(sv[kg][r] - mn);

        // tree sum
        float sm[16];
        #pragma unroll
        for (int r = 0; r < 16; ++r) sm[r] = sv[0][r] + sv[1][r];
        #pragma unroll
        for (int r = 0; r < 8; ++r) sm[r] += sm[r + 8];
        #pragma unroll
        for (int r = 0; r < 4; ++r) sm[r] += sm[r + 4];
        float rsum = (sm[0] + sm[1]) + (sm[2] + sm[3]);
        rsum += __shfl_xor(rsum, 32, 64);
        l_run = l_run * alpha + rsum;
        acc[0] *= alpha;
        acc[1] *= alpha;

        // ---- T12: in-register P -> B-operand fragments ----
        // lane holds sv[kg][g*4+q] = P[kk = kg*32 + 8g + 4*b5 + q][l31].
        // B-frag (kg,h), dest lane (b5,l31): bp[j] = P[kg*32+16h+8*b5+j][l31]
        //   dword0 = {u_low | vv_low}   dword2 = {u_high | vv_high}
        //   = permlane32_swap(u, vv)[0], [1]  (u = pk(gi=2h), vv = pk(gi=2h+1))
        bf16x8 bp[4];
        #pragma unroll
        for (int kg = 0; kg < 2; ++kg)
            #pragma unroll
            for (int h = 0; h < 2; ++h) {
                const unsigned int u  = cvtpk_bf16(sv[kg][8 * h + 0], sv[kg][8 * h + 1]);
                const unsigned int u2 = cvtpk_bf16(sv[kg][8 * h + 2], sv[kg][8 * h + 3]);
                const unsigned int vv = cvtpk_bf16(sv[kg][8 * h + 4], sv[kg][8 * h + 5]);
                const unsigned int v2 = cvtpk_bf16(sv[kg][8 * h + 6], sv[kg][8 * h + 7]);
                const u32x2 s1 = __builtin_amdgcn_permlane32_swap(u,  vv, false, false);
                const u32x2 s2 = __builtin_amdgcn_permlane32_swap(u2, v2, false, false);
                union { unsigned int w[4]; bf16x8 v8; } pkw;
                pkw.w[0] = s1[0]; pkw.w[1] = s2[0]; pkw.w[2] = s1[1]; pkw.w[3] = s2[1];
                bp[kg * 2 + h] = pkw.v8;
            }

        // bias prefetch for next step (sv dead now; nb free since step start)
        if (t < 7) {
            const int k0n = (t + 1) * 64;
            #pragma unroll
            for (int i = 0; i < 8; ++i)
                nb[i] = *(const f32x4*)(brow + k0n + (i >> 2) * 32 + (i & 3) * 8 + b5 * 4);
        }

        const bf16* Vc = Vs[cur];
        __builtin_amdgcn_s_setprio(1);
        #pragma unroll
        for (int c4 = 0; c4 < 4; ++c4) {
            #pragma unroll
            for (int dg = 0; dg < 2; ++dg) {
                const bf16x8 av = *(const bf16x8*)(Vc + dg * 2048 + c4 * 512 + lane * 8);
                acc[dg] = __builtin_amdgcn_mfma_f32_32x32x16_bf16(av, bp[c4], acc[dg], 0, 0, 0);
            }
        }
        __builtin_amdgcn_s_setprio(0);

        __asm__ volatile("s_waitcnt vmcnt(0)" ::: "memory");
        __syncthreads();
        cur ^= 1;
    }

    // ---- partial epilogue: normalized O (bf16) + (m, l) ----
    const float inv = 1.f / l_run;
    const size_t pbase = ((size_t)(ks * 16 + bh) * Q_ + qg) * 64;
    #pragma unroll
    for (int dg = 0; dg < 2; ++dg)
        #pragma unroll
        for (int gi = 0; gi < 4; ++gi) {
            const int d0 = dg * 32 + gi * 8 + b5 * 4;
            bf16x4 ov;
            #pragma unroll
            for (int r = 0; r < 4; ++r)
                ov[r] = (bf16)(acc[dg][gi * 4 + r] * inv);
            *(bf16x4*)(po + pbase + d0) = ov;
        }
    if (b5 == 0)
        ml[(size_t)(ks * 16 + bh) * Q_ + qg] = make_float2(m_run, l_run);
}

// ---------------------------------------------------------------------------
// Merge 4 split-K partials, apply gate, write bf16 [M,512].
// ---------------------------------------------------------------------------
__global__ __launch_bounds__(256)
void merge_kernel(const bf16* __restrict__ po, const float2* __restrict__ ml,
                  const bf16* __restrict__ g, bf16* __restrict__ og)
{
    const int gid = blockIdx.x * 256 + threadIdx.x;
    const int row = gid >> 3;             // bh*2048 + qg
    const int d8  = (gid & 7) * 8;
    const int bh  = row >> 11, qg = row & 2047;
    const int b   = bh >> 3, h = bh & 7;

    float2 m4[4];
    #pragma unroll
    for (int s = 0; s < 4; ++s) m4[s] = ml[(size_t)s * (16 * Q_) + row];
    const float M = fmaxf(fmaxf(m4[0].x, m4[1].x), fmaxf(m4[2].x, m4[3].x));
    float w[4], tot = 0.f;
    #pragma unroll
    for (int s = 0; s < 4; ++s) {
        w[s] = m4[s].y * __builtin_amdgcn_exp2f(m4[s].x - M);
        tot += w[s];
    }
    const float inv = 1.f / tot;
    #pragma unroll
    for (int s = 0; s < 4; ++s) w[s] *= inv;

    bf16x8 o[4];
    #pragma unroll
    for (int s = 0; s < 4; ++s)
        o[s] = *(const bf16x8*)(po + (size_t)s * (16 * Q_ * 64) + (size_t)row * 64 + d8);

    const size_t obase = ((size_t)(b * Q_ + qg)) * 512 + h * 64 + d8;
    const bf16x8 gv = *(const bf16x8*)(g + obase);
    bf16x8 ov;
    #pragma unroll
    for (int r = 0; r < 8; ++r) {
        float acc = 0.f;
        #pragma unroll
        for (int s = 0; s < 4; ++s) acc += (float)o[s][r] * w[s];
        ov[r] = (bf16)(acc * (float)gv[r]);
    }
    *(bf16x8*)(og + obase) = ov;
}

// ---------------------------------------------------------------------------
extern "C" void kernel_launch(void* const* d_in, const int* in_sizes, int n_in,
                              void* d_out, int out_size, void* d_ws, size_t ws_size,
                              hipStream_t stream)
{
    const float* q_x   = (const float*)d_in[0];
    const float* bias  = (const float*)d_in[2];
    const float* w_qkv = (const float*)d_in[3];
    const float* w_o   = (const float*)d_in[4];
    const float* b_o   = (const float*)d_in[5];
    const float* w_g   = (const float*)d_in[6];
    const float* b_g   = (const float*)d_in[7];
    float* out = (float*)d_out;

    char* ws = (char*)d_ws;
    bf16*   qxb  = (bf16*)(ws);                    // 4 MB  (dead after gemm0)
    bf16*   wcat = (bf16*)(ws + (4u  << 20));      // 2 MB  (dead after gemm0)
    bf16*   po   = (bf16*)(ws);                    // 16 MB partials (overlays qxb/wcat)
    bf16*   qb   = (bf16*)(ws + (16u << 20));      // 4 MB
    bf16*   kb   = (bf16*)(ws + (20u << 20));      // 4 MB  K frag-ordered
    bf16*   vb   = (bf16*)(ws + (24u << 20));      // 4 MB  V^T frag-ordered
    bf16*   gb   = (bf16*)(ws + (28u << 20));      // 4 MB  gate
    bf16*   ogb  = (bf16*)(ws + (32u << 20));      // 4 MB  gated O
    bf16*   wob  = (bf16*)(ws + (36u << 20));      // 0.5 MB
    float2* ml   = (float2*)(ws + (36u << 20) + (1u << 19));  // 1 MB -> ends 37.5 MB

    // 1) fp32 -> bf16 conversions
    convert_kernel<<<(S0 + S1 + S2 + S3) / (256 * 8), 256, 0, stream>>>(
        q_x, w_qkv, w_g, w_o, qxb, wcat, wob);
    // 2) fused QKV + gate projection (bf16 MFMA, coalesced epilogue)
    gemm_bf16<128, 128, 0><<<dim3(32, 16), 256, 0, stream>>>(
        qxb, wcat, b_g, nullptr, qb, kb, vb, gb);
    // 3) split-K flash attention partials (4-way split, 4 blocks/CU)
    attn_part<<<dim3(B_ * H_, Q_ / 128, 4), 256, 0, stream>>>(qb, kb, vb, bias, po, ml);
    // 4) merge partials + gate
    merge_kernel<<<(16 * Q_ * 8) / 256, 256, 0, stream>>>(po, ml, gb, ogb);
    // 5) output projection + b_o
    gemm_bf16<64, 128, 1><<<dim3(64, 4), 256, 0, stream>>>(
        ogb, wob, b_o, out, nullptr, nullptr, nullptr, nullptr);
}

// Round 4
// 182.193 us; speedup vs baseline: 1.5181x; 1.0802x over previous
//
#include <hip/hip_runtime.h>
#include <math.h>

#define B_  2
#define Q_  2048
#define CQ_ 512
#define H_  8
#define D_  64
#define M_  (B_*Q_)   // 4096
#define L2E 1.44269504088896f

typedef __bf16 bf16;
typedef __bf16 bf16x4 __attribute__((ext_vector_type(4)));
typedef __bf16 bf16x8 __attribute__((ext_vector_type(8)));
typedef float  f32x4  __attribute__((ext_vector_type(4)));
typedef float  f32x16 __attribute__((ext_vector_type(16)));
typedef unsigned int u32x2 __attribute__((ext_vector_type(2)));

// async global->LDS, 16 bytes per lane; lds dest = wave-uniform base + lane*16
__device__ __forceinline__ void gl_lds16(const bf16* g, bf16* l) {
    __builtin_amdgcn_global_load_lds(
        (const __attribute__((address_space(1))) unsigned int*)g,
        (__attribute__((address_space(3))) unsigned int*)l, 16, 0, 0);
}

// packed f32x2 -> bf16x2 (RNE), single VOP3
__device__ __forceinline__ unsigned int cvtpk_bf16(float lo, float hi) {
    unsigned int r;
    asm("v_cvt_pk_bf16_f32 %0, %1, %2" : "=v"(r) : "v"(lo), "v"(hi));
    return r;
}

// ---------------------------------------------------------------------------
// fp32 -> bf16 conversion
// ---------------------------------------------------------------------------
#define S0 (4096*512)    // q_x
#define S1 (1536*512)    // w_qkv
#define S2 (512*512)     // w_g
#define S3 (512*512)     // w_o
__global__ __launch_bounds__(256)
void convert_kernel(const float* __restrict__ qx, const float* __restrict__ wqkv,
                    const float* __restrict__ wg, const float* __restrict__ wo,
                    bf16* __restrict__ qxb, bf16* __restrict__ wcat, bf16* __restrict__ wob)
{
    const long long t = (long long)blockIdx.x * 256 + threadIdx.x;
    const long long e = t * 8;
    const float* src; bf16* dst;
    if (e < S0)                { src = qx + e;                  dst = qxb + e; }
    else if (e < S0 + S1)      { src = wqkv + (e - S0);         dst = wcat + (e - S0); }
    else if (e < S0 + S1 + S2) { src = wg + (e - S0 - S1);      dst = wcat + S1 + (e - S0 - S1); }
    else                       { src = wo + (e - S0 - S1 - S2); dst = wob + (e - S0 - S1 - S2); }
    const float4 a = *(const float4*)(src);
    const float4 b = *(const float4*)(src + 4);
    bf16x8 v;
    v[0] = (bf16)a.x; v[1] = (bf16)a.y; v[2] = (bf16)a.z; v[3] = (bf16)a.w;
    v[4] = (bf16)b.x; v[5] = (bf16)b.y; v[6] = (bf16)b.z; v[7] = (bf16)b.w;
    *(bf16x8*)dst = v;
}

// ---------------------------------------------------------------------------
// bf16 MFMA GEMM: C[M,N] = A[M,512] * W[N,512]^T, K=512, BK=32.
// For all parts except V we compute C^T (swapped mfma operands) so each lane
// holds 4 CONSECUTIVE n -> vector stores (b64/b128) instead of 64 scalars.
// EPI 0 (grid.y: 0-3 q, 4-7 k, 8-11 v, 12-15 gate), EPI 1: out = c + b_o.
// K frag order per (b,h), key kk, dim d:
//   off = (kk>>6)*4096 + ((kk>>5)&1)*2048 + (d>>4)*512 + ((d>>3)&1)*256
//       + (kk&31)*8 + (d&7)
// V^T frag order per (b,h):
//   off = (kk>>6)*4096 + (d>>5)*2048 + ((kk&63)>>4)*512 + ((kk>>3)&1)*256
//       + (d&31)*8 + (kk&7)
// ---------------------------------------------------------------------------
template<int BM, int BN, int EPI>
__global__ __launch_bounds__(256)
void gemm_bf16(const bf16* __restrict__ A, const bf16* __restrict__ W,
               const float* __restrict__ bvec, float* __restrict__ fout,
               bf16* __restrict__ qb, bf16* __restrict__ kb, bf16* __restrict__ vb,
               bf16* __restrict__ gb)
{
    constexpr int MI = BM / 32, NJ = BN / 32;
    __shared__ __align__(16) bf16 As[BM * 32];
    __shared__ __align__(16) bf16 Bs[BN * 32];

    const int t = threadIdx.x;
    const int w = t >> 6, lane = t & 63;
    const int l15 = lane & 15, quad = lane >> 4;
    const int wm = w & 1, wn = w >> 1;
    const int bm = blockIdx.x * BM;
    const int bn = blockIdx.y * BN;
    const bool swapped = (EPI == 1) || ((bn >> 9) != 2);

    f32x4 acc[MI][NJ] = {};

    const int rr = t >> 2;
    const int cc = (t & 3) * 8;

    for (int k0 = 0; k0 < 512; k0 += 32) {
        #pragma unroll
        for (int i = 0; i < BM / 64; ++i)
            gl_lds16(A + (size_t)(bm + i * 64 + rr) * 512 + k0 + cc,
                     As + (i * 64 + w * 16) * 32);
        #pragma unroll
        for (int i = 0; i < BN / 64; ++i)
            gl_lds16(W + (size_t)(bn + i * 64 + rr) * 512 + k0 + cc,
                     Bs + (i * 64 + w * 16) * 32);
        __asm__ volatile("s_waitcnt vmcnt(0)" ::: "memory");
        __syncthreads();

        bf16x8 af[MI], bfr[NJ];
        #pragma unroll
        for (int i = 0; i < MI; ++i)
            af[i] = *(const bf16x8*)(As + (wm * (BM / 2) + i * 16 + l15) * 32 + quad * 8);
        #pragma unroll
        for (int j = 0; j < NJ; ++j)
            bfr[j] = *(const bf16x8*)(Bs + (wn * (BN / 2) + j * 16 + l15) * 32 + quad * 8);
        if (swapped) {
            #pragma unroll
            for (int i = 0; i < MI; ++i)
                #pragma unroll
                for (int j = 0; j < NJ; ++j)
                    acc[i][j] = __builtin_amdgcn_mfma_f32_16x16x32_bf16(bfr[j], af[i], acc[i][j], 0, 0, 0);
        } else {
            #pragma unroll
            for (int i = 0; i < MI; ++i)
                #pragma unroll
                for (int j = 0; j < NJ; ++j)
                    acc[i][j] = __builtin_amdgcn_mfma_f32_16x16x32_bf16(af[i], bfr[j], acc[i][j], 0, 0, 0);
        }
        __syncthreads();
    }

    if (swapped) {
        #pragma unroll
        for (int i = 0; i < MI; ++i) {
            const int m = bm + wm * (BM / 2) + i * 16 + l15;
            const int b = m >> 11, qq = m & 2047;
            #pragma unroll
            for (int j = 0; j < NJ; ++j) {
                const int n0 = bn + wn * (BN / 2) + j * 16 + quad * 4;
                const f32x4 cv = acc[i][j];
                if constexpr (EPI == 1) {
                    float4 st;
                    st.x = cv[0] + bvec[n0 + 0];
                    st.y = cv[1] + bvec[n0 + 1];
                    st.z = cv[2] + bvec[n0 + 2];
                    st.w = cv[3] + bvec[n0 + 3];
                    *(float4*)(fout + (size_t)m * 512 + n0) = st;
                } else {
                    const int part = n0 >> 9;
                    if (part == 0) {
                        const int h = (n0 >> 6) & 7, d0 = n0 & 63;
                        bf16x4 q4;
                        #pragma unroll
                        for (int r = 0; r < 4; ++r) q4[r] = (bf16)(cv[r] * (0.125f * L2E));
                        *(bf16x4*)(qb + (size_t)(b * H_ + h) * (Q_ * D_) + (size_t)qq * 64 + d0) = q4;
                    } else if (part == 1) {
                        const int h = (n0 >> 6) & 7, d0 = n0 & 63;
                        const size_t off = (size_t)(b * H_ + h) * (Q_ * D_)
                            + (qq >> 6) * 4096 + ((qq >> 5) & 1) * 2048
                            + (d0 >> 4) * 512 + ((d0 >> 3) & 1) * 256
                            + (qq & 31) * 8 + (d0 & 7);
                        bf16x4 k4;
                        #pragma unroll
                        for (int r = 0; r < 4; ++r) k4[r] = (bf16)cv[r];
                        *(bf16x4*)(kb + off) = k4;
                    } else {
                        const int gcol = n0 & 511;
                        const float4 bv4 = *(const float4*)(bvec + gcol);
                        bf16x4 g4;
                        g4[0] = (bf16)(1.f / (1.f + __expf(-(cv[0] + bv4.x))));
                        g4[1] = (bf16)(1.f / (1.f + __expf(-(cv[1] + bv4.y))));
                        g4[2] = (bf16)(1.f / (1.f + __expf(-(cv[2] + bv4.z))));
                        g4[3] = (bf16)(1.f / (1.f + __expf(-(cv[3] + bv4.w))));
                        *(bf16x4*)(gb + (size_t)m * 512 + gcol) = g4;
                    }
                }
            }
        }
    } else {
        // V part, normal orientation: lane holds 4 consecutive qq for fixed d
        #pragma unroll
        for (int i = 0; i < MI; ++i) {
            const int m0 = bm + wm * (BM / 2) + i * 16 + quad * 4;
            const int b = m0 >> 11, qq0 = m0 & 2047;
            #pragma unroll
            for (int j = 0; j < NJ; ++j) {
                const int n = bn + wn * (BN / 2) + j * 16 + l15;
                const int h = (n >> 6) & 7, d = n & 63;
                const size_t off = (size_t)(b * H_ + h) * (Q_ * D_)
                    + (qq0 >> 6) * 4096 + (d >> 5) * 2048
                    + ((qq0 & 63) >> 4) * 512 + ((qq0 >> 3) & 1) * 256
                    + (d & 31) * 8 + (qq0 & 7);
                bf16x4 v4;
                #pragma unroll
                for (int r = 0; r < 4; ++r) v4[r] = (bf16)acc[i][j][r];
                *(bf16x4*)(vb + off) = v4;
            }
        }
    }
}

// ---------------------------------------------------------------------------
// Split-K MFMA flash attention (32x32x16, transposed dataflow S^T/O^T).
// Grid (16 bh, 16 qt, 4 ks) = 1024 blocks; __launch_bounds__(256,3) -> 170-reg
// unified budget (r3 post-mortem: (256,4)'s 128-reg cap forced acc/sv into
// 64 AGPRs + 64 arch VGPRs and spilled the rest -> 22MB scratch writes).
// Block = 4 waves x 32 q-rows = 128 q; key slab = ks*512..+512, 8 steps.
// K/V LDS-staged in fragment order via global_load_lds (conflict-free),
// double-buffered, one barrier/step. P transpose IN-REGISTER via
// v_cvt_pk_bf16_f32 + permlane32_swap (T12).
//  - bias enters QK^T as the MFMA C-in (sv init = bias*L2E)
//  - single nb[8] bias set, refilled during PV phase; lifetimes don't overlap
// LDS = 32 KiB/block. Partial out: normalized O (bf16) + m,l.
// ---------------------------------------------------------------------------
__global__ __launch_bounds__(256, 3)
void attn_part(const bf16* __restrict__ qb, const bf16* __restrict__ kf,
               const bf16* __restrict__ vf, const float* __restrict__ bias,
               bf16* __restrict__ po, float2* __restrict__ ml)
{
    __shared__ __align__(16) bf16 Ks[2][4096];
    __shared__ __align__(16) bf16 Vs[2][4096];

    const int tid  = threadIdx.x;
    const int wv   = tid >> 6, lane = tid & 63;
    const int l31  = lane & 31, b5 = lane >> 5;
    const int x    = blockIdx.x;
    const int bh   = ((x & 7) << 1) | (x >> 3);   // XCD gets same-b head pair
    const int b    = bh >> 3;
    const int qg   = blockIdx.y * 128 + wv * 32 + l31;
    const int ks   = blockIdx.z;

    const bf16* qp = qb + ((size_t)bh * Q_ + qg) * D_;
    bf16x8 bq[4];
    #pragma unroll
    for (int c = 0; c < 4; ++c)
        bq[c] = *(const bf16x8*)(qp + c * 16 + b5 * 8);

    f32x16 acc[2] = {};
    float m_run = -INFINITY, l_run = 0.f;

    const bf16*  kfb  = kf + (size_t)bh * (Q_ * D_) + (size_t)ks * 8 * 4096;
    const bf16*  vfb  = vf + (size_t)bh * (Q_ * D_) + (size_t)ks * 8 * 4096;
    const float* brow = bias + ((size_t)b * Q_ + qg) * Q_ + ks * 512;

    f32x4 nb[8];

    #pragma unroll
    for (int p = 0; p < 2; ++p) {
        gl_lds16(kfb + (wv * 2 + p) * 512 + lane * 8, Ks[0] + (wv * 2 + p) * 512);
        gl_lds16(vfb + (wv * 2 + p) * 512 + lane * 8, Vs[0] + (wv * 2 + p) * 512);
    }
    #pragma unroll
    for (int i = 0; i < 8; ++i)
        nb[i] = *(const f32x4*)(brow + (i >> 2) * 32 + (i & 3) * 8 + b5 * 4);
    __asm__ volatile("s_waitcnt vmcnt(0)" ::: "memory");
    __syncthreads();

    int cur = 0;
    #pragma unroll 1
    for (int t = 0; t < 8; ++t) {
        // K/V prefetch for next step (no VGPR cost: direct-to-LDS)
        if (t < 7) {
            const size_t off = (size_t)(t + 1) * 4096;
            #pragma unroll
            for (int p = 0; p < 2; ++p) {
                gl_lds16(kfb + off + (wv * 2 + p) * 512 + lane * 8,
                         Ks[cur ^ 1] + (wv * 2 + p) * 512);
                gl_lds16(vfb + off + (wv * 2 + p) * 512 + lane * 8,
                         Vs[cur ^ 1] + (wv * 2 + p) * 512);
            }
        }

        // sv init = bias*L2E (MFMA C-in); nb dies here
        f32x16 sv[2];
        #pragma unroll
        for (int kg = 0; kg < 2; ++kg)
            #pragma unroll
            for (int r = 0; r < 16; ++r)
                sv[kg][r] = nb[kg * 4 + (r >> 2)][r & 3] * L2E;

        const bf16* Kc = Ks[cur];
        __builtin_amdgcn_s_setprio(1);
        #pragma unroll
        for (int kg = 0; kg < 2; ++kg)
            #pragma unroll
            for (int c = 0; c < 4; ++c) {
                const bf16x8 ak = *(const bf16x8*)(Kc + kg * 2048 + c * 512 + lane * 8);
                sv[kg] = __builtin_amdgcn_mfma_f32_32x32x16_bf16(ak, bq[c], sv[kg], 0, 0, 0);
            }
        __builtin_amdgcn_s_setprio(0);

        // tree max (depth ~5)
        float mx[16];
        #pragma unroll
        for (int r = 0; r < 16; ++r) mx[r] = fmaxf(sv[0][r], sv[1][r]);
        #pragma unroll
        for (int r = 0; r < 8; ++r) mx[r] = fmaxf(mx[r], mx[r + 8]);
        #pragma unroll
        for (int r = 0; r < 4; ++r) mx[r] = fmaxf(mx[r], mx[r + 4]);
        float tmax = fmaxf(fmaxf(mx[0], mx[1]), fmaxf(mx[2], mx[3]));
        tmax = fmaxf(tmax, __shfl_xor(tmax, 32, 64));

        const float mn = fmaxf(m_run, tmax);
        const float alpha = __builtin_amdgcn_exp2f(m_run - mn);
        m_run = mn;

        #pragma unroll
        for (int kg = 0; kg < 2; ++kg)
            #pragma unroll
            for (int r = 0; r < 16; ++r)
                sv[kg][r] = __builtin_amdgcn_exp2f(sv[kg][r] - mn);

        // tree sum
        float sm[16];
        #pragma unroll
        for (int r = 0; r < 16; ++r) sm[r] = sv[0][r] + sv[1][r];
        #pragma unroll
        for (int r = 0; r < 8; ++r) sm[r] += sm[r + 8];
        #pragma unroll
        for (int r = 0; r < 4; ++r) sm[r] += sm[r + 4];
        float rsum = (sm[0] + sm[1]) + (sm[2] + sm[3]);
        rsum += __shfl_xor(rsum, 32, 64);
        l_run = l_run * alpha + rsum;
        acc[0] *= alpha;
        acc[1] *= alpha;

        // ---- T12: in-register P -> B-operand fragments ----
        // lane holds sv[kg][g*4+q] = P[kk = kg*32 + 8g + 4*b5 + q][l31].
        // B-frag (kg,h), dest lane (b5,l31): bp[j] = P[kg*32+16h+8*b5+j][l31]
        //   dword0 = {u_low | vv_low}   dword2 = {u_high | vv_high}
        //   = permlane32_swap(u, vv)[0], [1]  (u = pk(gi=2h), vv = pk(gi=2h+1))
        bf16x8 bp[4];
        #pragma unroll
        for (int kg = 0; kg < 2; ++kg)
            #pragma unroll
            for (int h = 0; h < 2; ++h) {
                const unsigned int u  = cvtpk_bf16(sv[kg][8 * h + 0], sv[kg][8 * h + 1]);
                const unsigned int u2 = cvtpk_bf16(sv[kg][8 * h + 2], sv[kg][8 * h + 3]);
                const unsigned int vv = cvtpk_bf16(sv[kg][8 * h + 4], sv[kg][8 * h + 5]);
                const unsigned int v2 = cvtpk_bf16(sv[kg][8 * h + 6], sv[kg][8 * h + 7]);
                const u32x2 s1 = __builtin_amdgcn_permlane32_swap(u,  vv, false, false);
                const u32x2 s2 = __builtin_amdgcn_permlane32_swap(u2, v2, false, false);
                union { unsigned int w[4]; bf16x8 v8; } pkw;
                pkw.w[0] = s1[0]; pkw.w[1] = s2[0]; pkw.w[2] = s1[1]; pkw.w[3] = s2[1];
                bp[kg * 2 + h] = pkw.v8;
            }

        // bias prefetch for next step (sv dead now; nb free since step start)
        if (t < 7) {
            const int k0n = (t + 1) * 64;
            #pragma unroll
            for (int i = 0; i < 8; ++i)
                nb[i] = *(const f32x4*)(brow + k0n + (i >> 2) * 32 + (i & 3) * 8 + b5 * 4);
        }

        const bf16* Vc = Vs[cur];
        __builtin_amdgcn_s_setprio(1);
        #pragma unroll
        for (int c4 = 0; c4 < 4; ++c4) {
            #pragma unroll
            for (int dg = 0; dg < 2; ++dg) {
                const bf16x8 av = *(const bf16x8*)(Vc + dg * 2048 + c4 * 512 + lane * 8);
                acc[dg] = __builtin_amdgcn_mfma_f32_32x32x16_bf16(av, bp[c4], acc[dg], 0, 0, 0);
            }
        }
        __builtin_amdgcn_s_setprio(0);

        __asm__ volatile("s_waitcnt vmcnt(0)" ::: "memory");
        __syncthreads();
        cur ^= 1;
    }

    // ---- partial epilogue: normalized O (bf16) + (m, l) ----
    const float inv = 1.f / l_run;
    const size_t pbase = ((size_t)(ks * 16 + bh) * Q_ + qg) * 64;
    #pragma unroll
    for (int dg = 0; dg < 2; ++dg)
        #pragma unroll
        for (int gi = 0; gi < 4; ++gi) {
            const int d0 = dg * 32 + gi * 8 + b5 * 4;
            bf16x4 ov;
            #pragma unroll
            for (int r = 0; r < 4; ++r)
                ov[r] = (bf16)(acc[dg][gi * 4 + r] * inv);
            *(bf16x4*)(po + pbase + d0) = ov;
        }
    if (b5 == 0)
        ml[(size_t)(ks * 16 + bh) * Q_ + qg] = make_float2(m_run, l_run);
}

// ---------------------------------------------------------------------------
// Merge 4 split-K partials, apply gate, write bf16 [M,512].
// ---------------------------------------------------------------------------
__global__ __launch_bounds__(256)
void merge_kernel(const bf16* __restrict__ po, const float2* __restrict__ ml,
                  const bf16* __restrict__ g, bf16* __restrict__ og)
{
    const int gid = blockIdx.x * 256 + threadIdx.x;
    const int row = gid >> 3;             // bh*2048 + qg
    const int d8  = (gid & 7) * 8;
    const int bh  = row >> 11, qg = row & 2047;
    const int b   = bh >> 3, h = bh & 7;

    float2 m4[4];
    #pragma unroll
    for (int s = 0; s < 4; ++s) m4[s] = ml[(size_t)s * (16 * Q_) + row];
    const float M = fmaxf(fmaxf(m4[0].x, m4[1].x), fmaxf(m4[2].x, m4[3].x));
    float w[4], tot = 0.f;
    #pragma unroll
    for (int s = 0; s < 4; ++s) {
        w[s] = m4[s].y * __builtin_amdgcn_exp2f(m4[s].x - M);
        tot += w[s];
    }
    const float inv = 1.f / tot;
    #pragma unroll
    for (int s = 0; s < 4; ++s) w[s] *= inv;

    bf16x8 o[4];
    #pragma unroll
    for (int s = 0; s < 4; ++s)
        o[s] = *(const bf16x8*)(po + (size_t)s * (16 * Q_ * 64) + (size_t)row * 64 + d8);

    const size_t obase = ((size_t)(b * Q_ + qg)) * 512 + h * 64 + d8;
    const bf16x8 gv = *(const bf16x8*)(g + obase);
    bf16x8 ov;
    #pragma unroll
    for (int r = 0; r < 8; ++r) {
        float acc = 0.f;
        #pragma unroll
        for (int s = 0; s < 4; ++s) acc += (float)o[s][r] * w[s];
        ov[r] = (bf16)(acc * (float)gv[r]);
    }
    *(bf16x8*)(og + obase) = ov;
}

// ---------------------------------------------------------------------------
extern "C" void kernel_launch(void* const* d_in, const int* in_sizes, int n_in,
                              void* d_out, int out_size, void* d_ws, size_t ws_size,
                              hipStream_t stream)
{
    const float* q_x   = (const float*)d_in[0];
    const float* bias  = (const float*)d_in[2];
    const float* w_qkv = (const float*)d_in[3];
    const float* w_o   = (const float*)d_in[4];
    const float* b_o   = (const float*)d_in[5];
    const float* w_g   = (const float*)d_in[6];
    const float* b_g   = (const float*)d_in[7];
    float* out = (float*)d_out;

    char* ws = (char*)d_ws;
    bf16*   qxb  = (bf16*)(ws);                    // 4 MB  (dead after gemm0)
    bf16*   wcat = (bf16*)(ws + (4u  << 20));      // 2 MB  (dead after gemm0)
    bf16*   po   = (bf16*)(ws);                    // 16 MB partials (overlays qxb/wcat)
    bf16*   qb   = (bf16*)(ws + (16u << 20));      // 4 MB
    bf16*   kb   = (bf16*)(ws + (20u << 20));      // 4 MB  K frag-ordered
    bf16*   vb   = (bf16*)(ws + (24u << 20));      // 4 MB  V^T frag-ordered
    bf16*   gb   = (bf16*)(ws + (28u << 20));      // 4 MB  gate
    bf16*   ogb  = (bf16*)(ws + (32u << 20));      // 4 MB  gated O
    bf16*   wob  = (bf16*)(ws + (36u << 20));      // 0.5 MB
    float2* ml   = (float2*)(ws + (36u << 20) + (1u << 19));  // 1 MB -> ends 37.5 MB

    // 1) fp32 -> bf16 conversions
    convert_kernel<<<(S0 + S1 + S2 + S3) / (256 * 8), 256, 0, stream>>>(
        q_x, w_qkv, w_g, w_o, qxb, wcat, wob);
    // 2) fused QKV + gate projection (bf16 MFMA, coalesced epilogue)
    gemm_bf16<128, 128, 0><<<dim3(32, 16), 256, 0, stream>>>(
        qxb, wcat, b_g, nullptr, qb, kb, vb, gb);
    // 3) split-K flash attention partials (4-way split, 170-reg budget)
    attn_part<<<dim3(B_ * H_, Q_ / 128, 4), 256, 0, stream>>>(qb, kb, vb, bias, po, ml);
    // 4) merge partials + gate
    merge_kernel<<<(16 * Q_ * 8) / 256, 256, 0, stream>>>(po, ml, gb, ogb);
    // 5) output projection + b_o
    gemm_bf16<64, 128, 1><<<dim3(64, 4), 256, 0, stream>>>(
        ogb, wob, b_o, out, nullptr, nullptr, nullptr, nullptr);
}

// Round 5
// 181.498 us; speedup vs baseline: 1.5240x; 1.0038x over previous
//
#include <hip/hip_runtime.h>
#include <math.h>

#define B_  2
#define Q_  2048
#define CQ_ 512
#define H_  8
#define D_  64
#define M_  (B_*Q_)   // 4096
#define L2E 1.44269504088896f

typedef __bf16 bf16;
typedef __bf16 bf16x4 __attribute__((ext_vector_type(4)));
typedef __bf16 bf16x8 __attribute__((ext_vector_type(8)));
typedef float  f32x4  __attribute__((ext_vector_type(4)));
typedef float  f32x16 __attribute__((ext_vector_type(16)));
typedef unsigned int u32x2 __attribute__((ext_vector_type(2)));

// async global->LDS, 16 bytes per lane; lds dest = wave-uniform base + lane*16
__device__ __forceinline__ void gl_lds16(const bf16* g, bf16* l) {
    __builtin_amdgcn_global_load_lds(
        (const __attribute__((address_space(1))) unsigned int*)g,
        (__attribute__((address_space(3))) unsigned int*)l, 16, 0, 0);
}

// packed f32x2 -> bf16x2 (RNE), single VOP3
__device__ __forceinline__ unsigned int cvtpk_bf16(float lo, float hi) {
    unsigned int r;
    asm("v_cvt_pk_bf16_f32 %0, %1, %2" : "=v"(r) : "v"(lo), "v"(hi));
    return r;
}

// ---------------------------------------------------------------------------
// fp32 -> bf16 conversion
// ---------------------------------------------------------------------------
#define S0 (4096*512)    // q_x
#define S1 (1536*512)    // w_qkv
#define S2 (512*512)     // w_g
#define S3 (512*512)     // w_o
__global__ __launch_bounds__(256)
void convert_kernel(const float* __restrict__ qx, const float* __restrict__ wqkv,
                    const float* __restrict__ wg, const float* __restrict__ wo,
                    bf16* __restrict__ qxb, bf16* __restrict__ wcat, bf16* __restrict__ wob)
{
    const long long t = (long long)blockIdx.x * 256 + threadIdx.x;
    const long long e = t * 8;
    const float* src; bf16* dst;
    if (e < S0)                { src = qx + e;                  dst = qxb + e; }
    else if (e < S0 + S1)      { src = wqkv + (e - S0);         dst = wcat + (e - S0); }
    else if (e < S0 + S1 + S2) { src = wg + (e - S0 - S1);      dst = wcat + S1 + (e - S0 - S1); }
    else                       { src = wo + (e - S0 - S1 - S2); dst = wob + (e - S0 - S1 - S2); }
    const float4 a = *(const float4*)(src);
    const float4 b = *(const float4*)(src + 4);
    bf16x8 v;
    v[0] = (bf16)a.x; v[1] = (bf16)a.y; v[2] = (bf16)a.z; v[3] = (bf16)a.w;
    v[4] = (bf16)b.x; v[5] = (bf16)b.y; v[6] = (bf16)b.z; v[7] = (bf16)b.w;
    *(bf16x8*)dst = v;
}

// ---------------------------------------------------------------------------
// bf16 MFMA GEMM: C[M,N] = A[M,512] * W[N,512]^T, K=512, BK=32.
// For all parts except V we compute C^T (swapped mfma operands) so each lane
// holds 4 CONSECUTIVE n -> vector stores (b64/b128) instead of 64 scalars.
// EPI 0 (grid.y: 0-3 q, 4-7 k, 8-11 v, 12-15 gate), EPI 1: out = c + b_o.
// K frag order per (b,h), key kk, dim d:
//   off = (kk>>6)*4096 + ((kk>>5)&1)*2048 + (d>>4)*512 + ((d>>3)&1)*256
//       + (kk&31)*8 + (d&7)
// V^T frag order per (b,h):
//   off = (kk>>6)*4096 + (d>>5)*2048 + ((kk&63)>>4)*512 + ((kk>>3)&1)*256
//       + (d&31)*8 + (kk&7)
// ---------------------------------------------------------------------------
template<int BM, int BN, int EPI>
__global__ __launch_bounds__(256)
void gemm_bf16(const bf16* __restrict__ A, const bf16* __restrict__ W,
               const float* __restrict__ bvec, float* __restrict__ fout,
               bf16* __restrict__ qb, bf16* __restrict__ kb, bf16* __restrict__ vb,
               bf16* __restrict__ gb)
{
    constexpr int MI = BM / 32, NJ = BN / 32;
    __shared__ __align__(16) bf16 As[BM * 32];
    __shared__ __align__(16) bf16 Bs[BN * 32];

    const int t = threadIdx.x;
    const int w = t >> 6, lane = t & 63;
    const int l15 = lane & 15, quad = lane >> 4;
    const int wm = w & 1, wn = w >> 1;
    const int bm = blockIdx.x * BM;
    const int bn = blockIdx.y * BN;
    const bool swapped = (EPI == 1) || ((bn >> 9) != 2);

    f32x4 acc[MI][NJ] = {};

    const int rr = t >> 2;
    const int cc = (t & 3) * 8;

    for (int k0 = 0; k0 < 512; k0 += 32) {
        #pragma unroll
        for (int i = 0; i < BM / 64; ++i)
            gl_lds16(A + (size_t)(bm + i * 64 + rr) * 512 + k0 + cc,
                     As + (i * 64 + w * 16) * 32);
        #pragma unroll
        for (int i = 0; i < BN / 64; ++i)
            gl_lds16(W + (size_t)(bn + i * 64 + rr) * 512 + k0 + cc,
                     Bs + (i * 64 + w * 16) * 32);
        __asm__ volatile("s_waitcnt vmcnt(0)" ::: "memory");
        __syncthreads();

        bf16x8 af[MI], bfr[NJ];
        #pragma unroll
        for (int i = 0; i < MI; ++i)
            af[i] = *(const bf16x8*)(As + (wm * (BM / 2) + i * 16 + l15) * 32 + quad * 8);
        #pragma unroll
        for (int j = 0; j < NJ; ++j)
            bfr[j] = *(const bf16x8*)(Bs + (wn * (BN / 2) + j * 16 + l15) * 32 + quad * 8);
        if (swapped) {
            #pragma unroll
            for (int i = 0; i < MI; ++i)
                #pragma unroll
                for (int j = 0; j < NJ; ++j)
                    acc[i][j] = __builtin_amdgcn_mfma_f32_16x16x32_bf16(bfr[j], af[i], acc[i][j], 0, 0, 0);
        } else {
            #pragma unroll
            for (int i = 0; i < MI; ++i)
                #pragma unroll
                for (int j = 0; j < NJ; ++j)
                    acc[i][j] = __builtin_amdgcn_mfma_f32_16x16x32_bf16(af[i], bfr[j], acc[i][j], 0, 0, 0);
        }
        __syncthreads();
    }

    if (swapped) {
        #pragma unroll
        for (int i = 0; i < MI; ++i) {
            const int m = bm + wm * (BM / 2) + i * 16 + l15;
            const int b = m >> 11, qq = m & 2047;
            #pragma unroll
            for (int j = 0; j < NJ; ++j) {
                const int n0 = bn + wn * (BN / 2) + j * 16 + quad * 4;
                const f32x4 cv = acc[i][j];
                if constexpr (EPI == 1) {
                    float4 st;
                    st.x = cv[0] + bvec[n0 + 0];
                    st.y = cv[1] + bvec[n0 + 1];
                    st.z = cv[2] + bvec[n0 + 2];
                    st.w = cv[3] + bvec[n0 + 3];
                    *(float4*)(fout + (size_t)m * 512 + n0) = st;
                } else {
                    const int part = n0 >> 9;
                    if (part == 0) {
                        const int h = (n0 >> 6) & 7, d0 = n0 & 63;
                        bf16x4 q4;
                        #pragma unroll
                        for (int r = 0; r < 4; ++r) q4[r] = (bf16)(cv[r] * (0.125f * L2E));
                        *(bf16x4*)(qb + (size_t)(b * H_ + h) * (Q_ * D_) + (size_t)qq * 64 + d0) = q4;
                    } else if (part == 1) {
                        const int h = (n0 >> 6) & 7, d0 = n0 & 63;
                        const size_t off = (size_t)(b * H_ + h) * (Q_ * D_)
                            + (qq >> 6) * 4096 + ((qq >> 5) & 1) * 2048
                            + (d0 >> 4) * 512 + ((d0 >> 3) & 1) * 256
                            + (qq & 31) * 8 + (d0 & 7);
                        bf16x4 k4;
                        #pragma unroll
                        for (int r = 0; r < 4; ++r) k4[r] = (bf16)cv[r];
                        *(bf16x4*)(kb + off) = k4;
                    } else {
                        const int gcol = n0 & 511;
                        const float4 bv4 = *(const float4*)(bvec + gcol);
                        bf16x4 g4;
                        g4[0] = (bf16)(1.f / (1.f + __expf(-(cv[0] + bv4.x))));
                        g4[1] = (bf16)(1.f / (1.f + __expf(-(cv[1] + bv4.y))));
                        g4[2] = (bf16)(1.f / (1.f + __expf(-(cv[2] + bv4.z))));
                        g4[3] = (bf16)(1.f / (1.f + __expf(-(cv[3] + bv4.w))));
                        *(bf16x4*)(gb + (size_t)m * 512 + gcol) = g4;
                    }
                }
            }
        }
    } else {
        // V part, normal orientation: lane holds 4 consecutive qq for fixed d
        #pragma unroll
        for (int i = 0; i < MI; ++i) {
            const int m0 = bm + wm * (BM / 2) + i * 16 + quad * 4;
            const int b = m0 >> 11, qq0 = m0 & 2047;
            #pragma unroll
            for (int j = 0; j < NJ; ++j) {
                const int n = bn + wn * (BN / 2) + j * 16 + l15;
                const int h = (n >> 6) & 7, d = n & 63;
                const size_t off = (size_t)(b * H_ + h) * (Q_ * D_)
                    + (qq0 >> 6) * 4096 + (d >> 5) * 2048
                    + ((qq0 & 63) >> 4) * 512 + ((qq0 >> 3) & 1) * 256
                    + (d & 31) * 8 + (qq0 & 7);
                bf16x4 v4;
                #pragma unroll
                for (int r = 0; r < 4; ++r) v4[r] = (bf16)acc[i][j][r];
                *(bf16x4*)(vb + off) = v4;
            }
        }
    }
}

// ---------------------------------------------------------------------------
// Split-K MFMA flash attention (32x32x16, transposed dataflow S^T/O^T).
// Grid (16 bh, 16 qt, 4 ks) = 1024 blocks; __launch_bounds__(256,3).
// Block = 4 waves x 32 q-rows = 128 q; key slab = ks*512..+512, 8 steps.
// K/V LDS-staged in fragment order via global_load_lds (conflict-free),
// double-buffered. P transpose IN-REGISTER via cvt_pk + permlane32_swap (T12).
// T4 counted-vmcnt schedule (r4 post-mortem: vmcnt(0) drained the late-issued
// bias loads every step -> ~500cy barrier stall for all 4 waves):
//   per step, VMEM issue order = [4x gl_lds K/V, 8x bias dwordx4];
//   bias issued at TOP of step (right after sv-init frees nb) -> full-step
//   cover; end-of-step s_waitcnt vmcnt(8) completes ONLY the 4 K/V staging
//   loads (global loads max dwordx4 -> the 8-entry bias count can't merge);
//   bias rides across the barrier, compiler waits before next sv-init.
//   Empty memory-clobber asm fences pin the issue order.
// LDS = 32 KiB/block. Partial out: normalized O (bf16) + m,l.
// ---------------------------------------------------------------------------
__global__ __launch_bounds__(256, 3)
void attn_part(const bf16* __restrict__ qb, const bf16* __restrict__ kf,
               const bf16* __restrict__ vf, const float* __restrict__ bias,
               bf16* __restrict__ po, float2* __restrict__ ml)
{
    __shared__ __align__(16) bf16 Ks[2][4096];
    __shared__ __align__(16) bf16 Vs[2][4096];

    const int tid  = threadIdx.x;
    const int wv   = tid >> 6, lane = tid & 63;
    const int l31  = lane & 31, b5 = lane >> 5;
    const int x    = blockIdx.x;
    const int bh   = ((x & 7) << 1) | (x >> 3);   // XCD gets same-b head pair
    const int b    = bh >> 3;
    const int qg   = blockIdx.y * 128 + wv * 32 + l31;
    const int ks   = blockIdx.z;

    const bf16* qp = qb + ((size_t)bh * Q_ + qg) * D_;
    bf16x8 bq[4];
    #pragma unroll
    for (int c = 0; c < 4; ++c)
        bq[c] = *(const bf16x8*)(qp + c * 16 + b5 * 8);

    f32x16 acc[2] = {};
    float m_run = -INFINITY, l_run = 0.f;

    const bf16*  kfb  = kf + (size_t)bh * (Q_ * D_) + (size_t)ks * 8 * 4096;
    const bf16*  vfb  = vf + (size_t)bh * (Q_ * D_) + (size_t)ks * 8 * 4096;
    const float* brow = bias + ((size_t)b * Q_ + qg) * Q_ + ks * 512;

    f32x4 nb[8];

    #pragma unroll
    for (int p = 0; p < 2; ++p) {
        gl_lds16(kfb + (wv * 2 + p) * 512 + lane * 8, Ks[0] + (wv * 2 + p) * 512);
        gl_lds16(vfb + (wv * 2 + p) * 512 + lane * 8, Vs[0] + (wv * 2 + p) * 512);
    }
    #pragma unroll
    for (int i = 0; i < 8; ++i)
        nb[i] = *(const f32x4*)(brow + (i >> 2) * 32 + (i & 3) * 8 + b5 * 4);
    __asm__ volatile("s_waitcnt vmcnt(0)" ::: "memory");
    __syncthreads();

    int cur = 0;
    #pragma unroll 1
    for (int t = 0; t < 8; ++t) {
        // K/V prefetch for next step (direct-to-LDS; FIRST in VMEM queue)
        if (t < 7) {
            const size_t off = (size_t)(t + 1) * 4096;
            #pragma unroll
            for (int p = 0; p < 2; ++p) {
                gl_lds16(kfb + off + (wv * 2 + p) * 512 + lane * 8,
                         Ks[cur ^ 1] + (wv * 2 + p) * 512);
                gl_lds16(vfb + off + (wv * 2 + p) * 512 + lane * 8,
                         Vs[cur ^ 1] + (wv * 2 + p) * 512);
            }
        }
        __asm__ volatile("" ::: "memory");   // fence A: pin gl_lds first

        // sv init = bias*L2E (MFMA C-in); nb dies here
        f32x16 sv[2];
        #pragma unroll
        for (int kg = 0; kg < 2; ++kg)
            #pragma unroll
            for (int r = 0; r < 16; ++r)
                sv[kg][r] = nb[kg * 4 + (r >> 2)][r & 3] * L2E;

        // bias prefetch for next step, issued at TOP (full-step latency cover)
        if (t < 7) {
            const int k0n = (t + 1) * 64;
            #pragma unroll
            for (int i = 0; i < 8; ++i)
                nb[i] = *(const f32x4*)(brow + k0n + (i >> 2) * 32 + (i & 3) * 8 + b5 * 4);
        }
        __asm__ volatile("" ::: "memory");   // fence B: pin bias issue here

        const bf16* Kc = Ks[cur];
        __builtin_amdgcn_s_setprio(1);
        #pragma unroll
        for (int kg = 0; kg < 2; ++kg)
            #pragma unroll
            for (int c = 0; c < 4; ++c) {
                const bf16x8 ak = *(const bf16x8*)(Kc + kg * 2048 + c * 512 + lane * 8);
                sv[kg] = __builtin_amdgcn_mfma_f32_32x32x16_bf16(ak, bq[c], sv[kg], 0, 0, 0);
            }
        __builtin_amdgcn_s_setprio(0);

        // tree max (depth ~5)
        float mx[16];
        #pragma unroll
        for (int r = 0; r < 16; ++r) mx[r] = fmaxf(sv[0][r], sv[1][r]);
        #pragma unroll
        for (int r = 0; r < 8; ++r) mx[r] = fmaxf(mx[r], mx[r + 8]);
        #pragma unroll
        for (int r = 0; r < 4; ++r) mx[r] = fmaxf(mx[r], mx[r + 4]);
        float tmax = fmaxf(fmaxf(mx[0], mx[1]), fmaxf(mx[2], mx[3]));
        tmax = fmaxf(tmax, __shfl_xor(tmax, 32, 64));

        const float mn = fmaxf(m_run, tmax);
        const float alpha = __builtin_amdgcn_exp2f(m_run - mn);
        m_run = mn;

        #pragma unroll
        for (int kg = 0; kg < 2; ++kg)
            #pragma unroll
            for (int r = 0; r < 16; ++r)
                sv[kg][r] = __builtin_amdgcn_exp2f(sv[kg][r] - mn);

        // tree sum
        float sm[16];
        #pragma unroll
        for (int r = 0; r < 16; ++r) sm[r] = sv[0][r] + sv[1][r];
        #pragma unroll
        for (int r = 0; r < 8; ++r) sm[r] += sm[r + 8];
        #pragma unroll
        for (int r = 0; r < 4; ++r) sm[r] += sm[r + 4];
        float rsum = (sm[0] + sm[1]) + (sm[2] + sm[3]);
        rsum += __shfl_xor(rsum, 32, 64);
        l_run = l_run * alpha + rsum;
        acc[0] *= alpha;
        acc[1] *= alpha;

        // ---- T12: in-register P -> B-operand fragments ----
        // lane holds sv[kg][g*4+q] = P[kk = kg*32 + 8g + 4*b5 + q][l31].
        // B-frag (kg,h), dest lane (b5,l31): bp[j] = P[kg*32+16h+8*b5+j][l31]
        //   dword0 = {u_low | vv_low}   dword2 = {u_high | vv_high}
        //   = permlane32_swap(u, vv)[0], [1]  (u = pk(gi=2h), vv = pk(gi=2h+1))
        bf16x8 bp[4];
        #pragma unroll
        for (int kg = 0; kg < 2; ++kg)
            #pragma unroll
            for (int h = 0; h < 2; ++h) {
                const unsigned int u  = cvtpk_bf16(sv[kg][8 * h + 0], sv[kg][8 * h + 1]);
                const unsigned int u2 = cvtpk_bf16(sv[kg][8 * h + 2], sv[kg][8 * h + 3]);
                const unsigned int vv = cvtpk_bf16(sv[kg][8 * h + 4], sv[kg][8 * h + 5]);
                const unsigned int v2 = cvtpk_bf16(sv[kg][8 * h + 6], sv[kg][8 * h + 7]);
                const u32x2 s1 = __builtin_amdgcn_permlane32_swap(u,  vv, false, false);
                const u32x2 s2 = __builtin_amdgcn_permlane32_swap(u2, v2, false, false);
                union { unsigned int w[4]; bf16x8 v8; } pkw;
                pkw.w[0] = s1[0]; pkw.w[1] = s2[0]; pkw.w[2] = s1[1]; pkw.w[3] = s2[1];
                bp[kg * 2 + h] = pkw.v8;
            }

        const bf16* Vc = Vs[cur];
        __builtin_amdgcn_s_setprio(1);
        #pragma unroll
        for (int c4 = 0; c4 < 4; ++c4) {
            #pragma unroll
            for (int dg = 0; dg < 2; ++dg) {
                const bf16x8 av = *(const bf16x8*)(Vc + dg * 2048 + c4 * 512 + lane * 8);
                acc[dg] = __builtin_amdgcn_mfma_f32_32x32x16_bf16(av, bp[c4], acc[dg], 0, 0, 0);
            }
        }
        __builtin_amdgcn_s_setprio(0);

        // counted drain: completes only the 4 K/V gl_lds (oldest); the 8
        // bias loads stay in flight across the barrier (T4).
        __asm__ volatile("s_waitcnt vmcnt(8)" ::: "memory");
        __syncthreads();
        cur ^= 1;
    }

    // ---- partial epilogue: normalized O (bf16) + (m, l) ----
    const float inv = 1.f / l_run;
    const size_t pbase = ((size_t)(ks * 16 + bh) * Q_ + qg) * 64;
    #pragma unroll
    for (int dg = 0; dg < 2; ++dg)
        #pragma unroll
        for (int gi = 0; gi < 4; ++gi) {
            const int d0 = dg * 32 + gi * 8 + b5 * 4;
            bf16x4 ov;
            #pragma unroll
            for (int r = 0; r < 4; ++r)
                ov[r] = (bf16)(acc[dg][gi * 4 + r] * inv);
            *(bf16x4*)(po + pbase + d0) = ov;
        }
    if (b5 == 0)
        ml[(size_t)(ks * 16 + bh) * Q_ + qg] = make_float2(m_run, l_run);
}

// ---------------------------------------------------------------------------
// Merge 4 split-K partials, apply gate, write bf16 [M,512].
// ---------------------------------------------------------------------------
__global__ __launch_bounds__(256)
void merge_kernel(const bf16* __restrict__ po, const float2* __restrict__ ml,
                  const bf16* __restrict__ g, bf16* __restrict__ og)
{
    const int gid = blockIdx.x * 256 + threadIdx.x;
    const int row = gid >> 3;             // bh*2048 + qg
    const int d8  = (gid & 7) * 8;
    const int bh  = row >> 11, qg = row & 2047;
    const int b   = bh >> 3, h = bh & 7;

    float2 m4[4];
    #pragma unroll
    for (int s = 0; s < 4; ++s) m4[s] = ml[(size_t)s * (16 * Q_) + row];
    const float M = fmaxf(fmaxf(m4[0].x, m4[1].x), fmaxf(m4[2].x, m4[3].x));
    float w[4], tot = 0.f;
    #pragma unroll
    for (int s = 0; s < 4; ++s) {
        w[s] = m4[s].y * __builtin_amdgcn_exp2f(m4[s].x - M);
        tot += w[s];
    }
    const float inv = 1.f / tot;
    #pragma unroll
    for (int s = 0; s < 4; ++s) w[s] *= inv;

    bf16x8 o[4];
    #pragma unroll
    for (int s = 0; s < 4; ++s)
        o[s] = *(const bf16x8*)(po + (size_t)s * (16 * Q_ * 64) + (size_t)row * 64 + d8);

    const size_t obase = ((size_t)(b * Q_ + qg)) * 512 + h * 64 + d8;
    const bf16x8 gv = *(const bf16x8*)(g + obase);
    bf16x8 ov;
    #pragma unroll
    for (int r = 0; r < 8; ++r) {
        float acc = 0.f;
        #pragma unroll
        for (int s = 0; s < 4; ++s) acc += (float)o[s][r] * w[s];
        ov[r] = (bf16)(acc * (float)gv[r]);
    }
    *(bf16x8*)(og + obase) = ov;
}

// ---------------------------------------------------------------------------
extern "C" void kernel_launch(void* const* d_in, const int* in_sizes, int n_in,
                              void* d_out, int out_size, void* d_ws, size_t ws_size,
                              hipStream_t stream)
{
    const float* q_x   = (const float*)d_in[0];
    const float* bias  = (const float*)d_in[2];
    const float* w_qkv = (const float*)d_in[3];
    const float* w_o   = (const float*)d_in[4];
    const float* b_o   = (const float*)d_in[5];
    const float* w_g   = (const float*)d_in[6];
    const float* b_g   = (const float*)d_in[7];
    float* out = (float*)d_out;

    char* ws = (char*)d_ws;
    bf16*   qxb  = (bf16*)(ws);                    // 4 MB  (dead after gemm0)
    bf16*   wcat = (bf16*)(ws + (4u  << 20));      // 2 MB  (dead after gemm0)
    bf16*   po   = (bf16*)(ws);                    // 16 MB partials (overlays qxb/wcat)
    bf16*   qb   = (bf16*)(ws + (16u << 20));      // 4 MB
    bf16*   kb   = (bf16*)(ws + (20u << 20));      // 4 MB  K frag-ordered
    bf16*   vb   = (bf16*)(ws + (24u << 20));      // 4 MB  V^T frag-ordered
    bf16*   gb   = (bf16*)(ws + (28u << 20));      // 4 MB  gate
    bf16*   ogb  = (bf16*)(ws + (32u << 20));      // 4 MB  gated O
    bf16*   wob  = (bf16*)(ws + (36u << 20));      // 0.5 MB
    float2* ml   = (float2*)(ws + (36u << 20) + (1u << 19));  // 1 MB -> ends 37.5 MB

    // 1) fp32 -> bf16 conversions
    convert_kernel<<<(S0 + S1 + S2 + S3) / (256 * 8), 256, 0, stream>>>(
        q_x, w_qkv, w_g, w_o, qxb, wcat, wob);
    // 2) fused QKV + gate projection (bf16 MFMA, coalesced epilogue)
    gemm_bf16<128, 128, 0><<<dim3(32, 16), 256, 0, stream>>>(
        qxb, wcat, b_g, nullptr, qb, kb, vb, gb);
    // 3) split-K flash attention partials (4-way split, counted-vmcnt schedule)
    attn_part<<<dim3(B_ * H_, Q_ / 128, 4), 256, 0, stream>>>(qb, kb, vb, bias, po, ml);
    // 4) merge partials + gate
    merge_kernel<<<(16 * Q_ * 8) / 256, 256, 0, stream>>>(po, ml, gb, ogb);
    // 5) output projection + b_o
    gemm_bf16<64, 128, 1><<<dim3(64, 4), 256, 0, stream>>>(
        ogb, wob, b_o, out, nullptr, nullptr, nullptr, nullptr);
}

// Round 6
// 178.251 us; speedup vs baseline: 1.5517x; 1.0182x over previous
//
#include <hip/hip_runtime.h>
#include <math.h>

#define B_  2
#define Q_  2048
#define CQ_ 512
#define H_  8
#define D_  64
#define M_  (B_*Q_)   // 4096
#define L2E 1.44269504088896f

typedef __bf16 bf16;
typedef __bf16 bf16x4 __attribute__((ext_vector_type(4)));
typedef __bf16 bf16x8 __attribute__((ext_vector_type(8)));
typedef float  f32x4  __attribute__((ext_vector_type(4)));
typedef float  f32x16 __attribute__((ext_vector_type(16)));
typedef unsigned int u32x2 __attribute__((ext_vector_type(2)));

// async global->LDS, 16 bytes per lane; lds dest = wave-uniform base + lane*16
__device__ __forceinline__ void gl_lds16(const bf16* g, bf16* l) {
    __builtin_amdgcn_global_load_lds(
        (const __attribute__((address_space(1))) unsigned int*)g,
        (__attribute__((address_space(3))) unsigned int*)l, 16, 0, 0);
}

// packed f32x2 -> bf16x2 (RNE), single VOP3
__device__ __forceinline__ unsigned int cvtpk_bf16(float lo, float hi) {
    unsigned int r;
    asm("v_cvt_pk_bf16_f32 %0, %1, %2" : "=v"(r) : "v"(lo), "v"(hi));
    return r;
}

// ---------------------------------------------------------------------------
// fp32 -> bf16 conversion
// ---------------------------------------------------------------------------
#define S0 (4096*512)    // q_x
#define S1 (1536*512)    // w_qkv
#define S2 (512*512)     // w_g
#define S3 (512*512)     // w_o
__global__ __launch_bounds__(256)
void convert_kernel(const float* __restrict__ qx, const float* __restrict__ wqkv,
                    const float* __restrict__ wg, const float* __restrict__ wo,
                    bf16* __restrict__ qxb, bf16* __restrict__ wcat, bf16* __restrict__ wob)
{
    const long long t = (long long)blockIdx.x * 256 + threadIdx.x;
    const long long e = t * 8;
    const float* src; bf16* dst;
    if (e < S0)                { src = qx + e;                  dst = qxb + e; }
    else if (e < S0 + S1)      { src = wqkv + (e - S0);         dst = wcat + (e - S0); }
    else if (e < S0 + S1 + S2) { src = wg + (e - S0 - S1);      dst = wcat + S1 + (e - S0 - S1); }
    else                       { src = wo + (e - S0 - S1 - S2); dst = wob + (e - S0 - S1 - S2); }
    const float4 a = *(const float4*)(src);
    const float4 b = *(const float4*)(src + 4);
    bf16x8 v;
    v[0] = (bf16)a.x; v[1] = (bf16)a.y; v[2] = (bf16)a.z; v[3] = (bf16)a.w;
    v[4] = (bf16)b.x; v[5] = (bf16)b.y; v[6] = (bf16)b.z; v[7] = (bf16)b.w;
    *(bf16x8*)dst = v;
}

// ---------------------------------------------------------------------------
// bf16 MFMA GEMM: C[M,N] = A[M,512] * W[N,512]^T, K=512, BK=32.
// For all parts except V we compute C^T (swapped mfma operands) so each lane
// holds 4 CONSECUTIVE n -> vector stores (b64/b128) instead of 64 scalars.
// EPI 0 (grid.y: 0-3 q, 4-7 k, 8-11 v, 12-15 gate), EPI 1: out = c + b_o.
// K frag order per (b,h), key kk, dim d:
//   off = (kk>>6)*4096 + ((kk>>5)&1)*2048 + (d>>4)*512 + ((d>>3)&1)*256
//       + (kk&31)*8 + (d&7)
// V^T frag order per (b,h):
//   off = (kk>>6)*4096 + (d>>5)*2048 + ((kk&63)>>4)*512 + ((kk>>3)&1)*256
//       + (d&31)*8 + (kk&7)
// ---------------------------------------------------------------------------
template<int BM, int BN, int EPI>
__global__ __launch_bounds__(256)
void gemm_bf16(const bf16* __restrict__ A, const bf16* __restrict__ W,
               const float* __restrict__ bvec, float* __restrict__ fout,
               bf16* __restrict__ qb, bf16* __restrict__ kb, bf16* __restrict__ vb,
               bf16* __restrict__ gb)
{
    constexpr int MI = BM / 32, NJ = BN / 32;
    __shared__ __align__(16) bf16 As[BM * 32];
    __shared__ __align__(16) bf16 Bs[BN * 32];

    const int t = threadIdx.x;
    const int w = t >> 6, lane = t & 63;
    const int l15 = lane & 15, quad = lane >> 4;
    const int wm = w & 1, wn = w >> 1;
    const int bm = blockIdx.x * BM;
    const int bn = blockIdx.y * BN;
    const bool swapped = (EPI == 1) || ((bn >> 9) != 2);

    f32x4 acc[MI][NJ] = {};

    const int rr = t >> 2;
    const int cc = (t & 3) * 8;

    for (int k0 = 0; k0 < 512; k0 += 32) {
        #pragma unroll
        for (int i = 0; i < BM / 64; ++i)
            gl_lds16(A + (size_t)(bm + i * 64 + rr) * 512 + k0 + cc,
                     As + (i * 64 + w * 16) * 32);
        #pragma unroll
        for (int i = 0; i < BN / 64; ++i)
            gl_lds16(W + (size_t)(bn + i * 64 + rr) * 512 + k0 + cc,
                     Bs + (i * 64 + w * 16) * 32);
        __asm__ volatile("s_waitcnt vmcnt(0)" ::: "memory");
        __syncthreads();

        bf16x8 af[MI], bfr[NJ];
        #pragma unroll
        for (int i = 0; i < MI; ++i)
            af[i] = *(const bf16x8*)(As + (wm * (BM / 2) + i * 16 + l15) * 32 + quad * 8);
        #pragma unroll
        for (int j = 0; j < NJ; ++j)
            bfr[j] = *(const bf16x8*)(Bs + (wn * (BN / 2) + j * 16 + l15) * 32 + quad * 8);
        if (swapped) {
            #pragma unroll
            for (int i = 0; i < MI; ++i)
                #pragma unroll
                for (int j = 0; j < NJ; ++j)
                    acc[i][j] = __builtin_amdgcn_mfma_f32_16x16x32_bf16(bfr[j], af[i], acc[i][j], 0, 0, 0);
        } else {
            #pragma unroll
            for (int i = 0; i < MI; ++i)
                #pragma unroll
                for (int j = 0; j < NJ; ++j)
                    acc[i][j] = __builtin_amdgcn_mfma_f32_16x16x32_bf16(af[i], bfr[j], acc[i][j], 0, 0, 0);
        }
        __syncthreads();
    }

    if (swapped) {
        #pragma unroll
        for (int i = 0; i < MI; ++i) {
            const int m = bm + wm * (BM / 2) + i * 16 + l15;
            const int b = m >> 11, qq = m & 2047;
            #pragma unroll
            for (int j = 0; j < NJ; ++j) {
                const int n0 = bn + wn * (BN / 2) + j * 16 + quad * 4;
                const f32x4 cv = acc[i][j];
                if constexpr (EPI == 1) {
                    float4 st;
                    st.x = cv[0] + bvec[n0 + 0];
                    st.y = cv[1] + bvec[n0 + 1];
                    st.z = cv[2] + bvec[n0 + 2];
                    st.w = cv[3] + bvec[n0 + 3];
                    *(float4*)(fout + (size_t)m * 512 + n0) = st;
                } else {
                    const int part = n0 >> 9;
                    if (part == 0) {
                        const int h = (n0 >> 6) & 7, d0 = n0 & 63;
                        bf16x4 q4;
                        #pragma unroll
                        for (int r = 0; r < 4; ++r) q4[r] = (bf16)(cv[r] * (0.125f * L2E));
                        *(bf16x4*)(qb + (size_t)(b * H_ + h) * (Q_ * D_) + (size_t)qq * 64 + d0) = q4;
                    } else if (part == 1) {
                        const int h = (n0 >> 6) & 7, d0 = n0 & 63;
                        const size_t off = (size_t)(b * H_ + h) * (Q_ * D_)
                            + (qq >> 6) * 4096 + ((qq >> 5) & 1) * 2048
                            + (d0 >> 4) * 512 + ((d0 >> 3) & 1) * 256
                            + (qq & 31) * 8 + (d0 & 7);
                        bf16x4 k4;
                        #pragma unroll
                        for (int r = 0; r < 4; ++r) k4[r] = (bf16)cv[r];
                        *(bf16x4*)(kb + off) = k4;
                    } else {
                        const int gcol = n0 & 511;
                        const float4 bv4 = *(const float4*)(bvec + gcol);
                        bf16x4 g4;
                        g4[0] = (bf16)(1.f / (1.f + __expf(-(cv[0] + bv4.x))));
                        g4[1] = (bf16)(1.f / (1.f + __expf(-(cv[1] + bv4.y))));
                        g4[2] = (bf16)(1.f / (1.f + __expf(-(cv[2] + bv4.z))));
                        g4[3] = (bf16)(1.f / (1.f + __expf(-(cv[3] + bv4.w))));
                        *(bf16x4*)(gb + (size_t)m * 512 + gcol) = g4;
                    }
                }
            }
        }
    } else {
        // V part, normal orientation: lane holds 4 consecutive qq for fixed d
        #pragma unroll
        for (int i = 0; i < MI; ++i) {
            const int m0 = bm + wm * (BM / 2) + i * 16 + quad * 4;
            const int b = m0 >> 11, qq0 = m0 & 2047;
            #pragma unroll
            for (int j = 0; j < NJ; ++j) {
                const int n = bn + wn * (BN / 2) + j * 16 + l15;
                const int h = (n >> 6) & 7, d = n & 63;
                const size_t off = (size_t)(b * H_ + h) * (Q_ * D_)
                    + (qq0 >> 6) * 4096 + (d >> 5) * 2048
                    + ((qq0 & 63) >> 4) * 512 + ((qq0 >> 3) & 1) * 256
                    + (d & 31) * 8 + (qq0 & 7);
                bf16x4 v4;
                #pragma unroll
                for (int r = 0; r < 4; ++r) v4[r] = (bf16)acc[i][j][r];
                *(bf16x4*)(vb + off) = v4;
            }
        }
    }
}

// ---------------------------------------------------------------------------
// Split-K MFMA flash attention (32x32x16, transposed dataflow S^T/O^T).
// Grid (16 bh, 16 qt, 3 ks) = 768 blocks = EXACTLY 3 blocks/CU on 256 CUs:
// single co-resident cohort, no residency tail (r5 post-mortem: 1024 blocks
// at 3/CU ran as 768 + 256-block tail -> time-avg occupancy 23%, half the
// kernel with the machine 3/4 empty). 32 key-steps split 11/11/10 per ks.
// Block = 4 waves x 32 q-rows = 128 q.
// K/V LDS-staged in fragment order via global_load_lds (conflict-free),
// double-buffered. P transpose IN-REGISTER via cvt_pk + permlane32_swap (T12).
// T4 counted-vmcnt: per step VMEM order = [4x gl_lds K/V, 8x bias dwordx4];
// end-of-step s_waitcnt vmcnt(8) completes only the K/V staging; bias rides
// across the barrier. Bias enters QK^T as MFMA C-in (sv init = bias*L2E).
// LDS = 32 KiB/block. Partial out: normalized O (bf16) + m,l.
// ---------------------------------------------------------------------------
__global__ __launch_bounds__(256, 3)
void attn_part(const bf16* __restrict__ qb, const bf16* __restrict__ kf,
               const bf16* __restrict__ vf, const float* __restrict__ bias,
               bf16* __restrict__ po, float2* __restrict__ ml)
{
    __shared__ __align__(16) bf16 Ks[2][4096];
    __shared__ __align__(16) bf16 Vs[2][4096];

    const int tid  = threadIdx.x;
    const int wv   = tid >> 6, lane = tid & 63;
    const int l31  = lane & 31, b5 = lane >> 5;
    const int x    = blockIdx.x;
    const int bh   = ((x & 7) << 1) | (x >> 3);   // XCD gets same-b head pair
    const int b    = bh >> 3;
    const int qg   = blockIdx.y * 128 + wv * 32 + l31;
    const int ks   = blockIdx.z;
    const int t0   = ks * 11;                     // start step (64-key units)
    const int nt   = (ks < 2) ? 11 : 10;          // steps this slice (11/11/10)

    const bf16* qp = qb + ((size_t)bh * Q_ + qg) * D_;
    bf16x8 bq[4];
    #pragma unroll
    for (int c = 0; c < 4; ++c)
        bq[c] = *(const bf16x8*)(qp + c * 16 + b5 * 8);

    f32x16 acc[2] = {};
    float m_run = -INFINITY, l_run = 0.f;

    const bf16*  kfb  = kf + (size_t)bh * (Q_ * D_) + (size_t)t0 * 4096;
    const bf16*  vfb  = vf + (size_t)bh * (Q_ * D_) + (size_t)t0 * 4096;
    const float* brow = bias + ((size_t)b * Q_ + qg) * Q_ + t0 * 64;

    f32x4 nb[8];

    #pragma unroll
    for (int p = 0; p < 2; ++p) {
        gl_lds16(kfb + (wv * 2 + p) * 512 + lane * 8, Ks[0] + (wv * 2 + p) * 512);
        gl_lds16(vfb + (wv * 2 + p) * 512 + lane * 8, Vs[0] + (wv * 2 + p) * 512);
    }
    #pragma unroll
    for (int i = 0; i < 8; ++i)
        nb[i] = *(const f32x4*)(brow + (i >> 2) * 32 + (i & 3) * 8 + b5 * 4);
    __asm__ volatile("s_waitcnt vmcnt(0)" ::: "memory");
    __syncthreads();

    int cur = 0;
    #pragma unroll 1
    for (int t = 0; t < nt; ++t) {
        // K/V prefetch for next step (direct-to-LDS; FIRST in VMEM queue)
        if (t < nt - 1) {
            const size_t off = (size_t)(t + 1) * 4096;
            #pragma unroll
            for (int p = 0; p < 2; ++p) {
                gl_lds16(kfb + off + (wv * 2 + p) * 512 + lane * 8,
                         Ks[cur ^ 1] + (wv * 2 + p) * 512);
                gl_lds16(vfb + off + (wv * 2 + p) * 512 + lane * 8,
                         Vs[cur ^ 1] + (wv * 2 + p) * 512);
            }
        }
        __asm__ volatile("" ::: "memory");   // fence A: pin gl_lds first

        // sv init = bias*L2E (MFMA C-in); nb dies here
        f32x16 sv[2];
        #pragma unroll
        for (int kg = 0; kg < 2; ++kg)
            #pragma unroll
            for (int r = 0; r < 16; ++r)
                sv[kg][r] = nb[kg * 4 + (r >> 2)][r & 3] * L2E;

        // bias prefetch for next step, issued at TOP (full-step latency cover)
        if (t < nt - 1) {
            const int k0n = (t + 1) * 64;
            #pragma unroll
            for (int i = 0; i < 8; ++i)
                nb[i] = *(const f32x4*)(brow + k0n + (i >> 2) * 32 + (i & 3) * 8 + b5 * 4);
        }
        __asm__ volatile("" ::: "memory");   // fence B: pin bias issue here

        const bf16* Kc = Ks[cur];
        __builtin_amdgcn_s_setprio(1);
        #pragma unroll
        for (int kg = 0; kg < 2; ++kg)
            #pragma unroll
            for (int c = 0; c < 4; ++c) {
                const bf16x8 ak = *(const bf16x8*)(Kc + kg * 2048 + c * 512 + lane * 8);
                sv[kg] = __builtin_amdgcn_mfma_f32_32x32x16_bf16(ak, bq[c], sv[kg], 0, 0, 0);
            }
        __builtin_amdgcn_s_setprio(0);

        // tree max (depth ~5)
        float mx[16];
        #pragma unroll
        for (int r = 0; r < 16; ++r) mx[r] = fmaxf(sv[0][r], sv[1][r]);
        #pragma unroll
        for (int r = 0; r < 8; ++r) mx[r] = fmaxf(mx[r], mx[r + 8]);
        #pragma unroll
        for (int r = 0; r < 4; ++r) mx[r] = fmaxf(mx[r], mx[r + 4]);
        float tmax = fmaxf(fmaxf(mx[0], mx[1]), fmaxf(mx[2], mx[3]));
        tmax = fmaxf(tmax, __shfl_xor(tmax, 32, 64));

        const float mn = fmaxf(m_run, tmax);
        const float alpha = __builtin_amdgcn_exp2f(m_run - mn);
        m_run = mn;

        #pragma unroll
        for (int kg = 0; kg < 2; ++kg)
            #pragma unroll
            for (int r = 0; r < 16; ++r)
                sv[kg][r] = __builtin_amdgcn_exp2f(sv[kg][r] - mn);

        // tree sum
        float sm[16];
        #pragma unroll
        for (int r = 0; r < 16; ++r) sm[r] = sv[0][r] + sv[1][r];
        #pragma unroll
        for (int r = 0; r < 8; ++r) sm[r] += sm[r + 8];
        #pragma unroll
        for (int r = 0; r < 4; ++r) sm[r] += sm[r + 4];
        float rsum = (sm[0] + sm[1]) + (sm[2] + sm[3]);
        rsum += __shfl_xor(rsum, 32, 64);
        l_run = l_run * alpha + rsum;
        acc[0] *= alpha;
        acc[1] *= alpha;

        // ---- T12: in-register P -> B-operand fragments ----
        // lane holds sv[kg][g*4+q] = P[kk = kg*32 + 8g + 4*b5 + q][l31].
        // B-frag (kg,h), dest lane (b5,l31): bp[j] = P[kg*32+16h+8*b5+j][l31]
        //   dword0 = {u_low | vv_low}   dword2 = {u_high | vv_high}
        //   = permlane32_swap(u, vv)[0], [1]  (u = pk(gi=2h), vv = pk(gi=2h+1))
        bf16x8 bp[4];
        #pragma unroll
        for (int kg = 0; kg < 2; ++kg)
            #pragma unroll
            for (int h = 0; h < 2; ++h) {
                const unsigned int u  = cvtpk_bf16(sv[kg][8 * h + 0], sv[kg][8 * h + 1]);
                const unsigned int u2 = cvtpk_bf16(sv[kg][8 * h + 2], sv[kg][8 * h + 3]);
                const unsigned int vv = cvtpk_bf16(sv[kg][8 * h + 4], sv[kg][8 * h + 5]);
                const unsigned int v2 = cvtpk_bf16(sv[kg][8 * h + 6], sv[kg][8 * h + 7]);
                const u32x2 s1 = __builtin_amdgcn_permlane32_swap(u,  vv, false, false);
                const u32x2 s2 = __builtin_amdgcn_permlane32_swap(u2, v2, false, false);
                union { unsigned int w[4]; bf16x8 v8; } pkw;
                pkw.w[0] = s1[0]; pkw.w[1] = s2[0]; pkw.w[2] = s1[1]; pkw.w[3] = s2[1];
                bp[kg * 2 + h] = pkw.v8;
            }

        const bf16* Vc = Vs[cur];
        __builtin_amdgcn_s_setprio(1);
        #pragma unroll
        for (int c4 = 0; c4 < 4; ++c4) {
            #pragma unroll
            for (int dg = 0; dg < 2; ++dg) {
                const bf16x8 av = *(const bf16x8*)(Vc + dg * 2048 + c4 * 512 + lane * 8);
                acc[dg] = __builtin_amdgcn_mfma_f32_32x32x16_bf16(av, bp[c4], acc[dg], 0, 0, 0);
            }
        }
        __builtin_amdgcn_s_setprio(0);

        // counted drain: completes only the 4 K/V gl_lds (oldest); the 8
        // bias loads stay in flight across the barrier (T4).
        __asm__ volatile("s_waitcnt vmcnt(8)" ::: "memory");
        __syncthreads();
        cur ^= 1;
    }

    // ---- partial epilogue: normalized O (bf16) + (m, l) ----
    const float inv = 1.f / l_run;
    const size_t pbase = ((size_t)(ks * 16 + bh) * Q_ + qg) * 64;
    #pragma unroll
    for (int dg = 0; dg < 2; ++dg)
        #pragma unroll
        for (int gi = 0; gi < 4; ++gi) {
            const int d0 = dg * 32 + gi * 8 + b5 * 4;
            bf16x4 ov;
            #pragma unroll
            for (int r = 0; r < 4; ++r)
                ov[r] = (bf16)(acc[dg][gi * 4 + r] * inv);
            *(bf16x4*)(po + pbase + d0) = ov;
        }
    if (b5 == 0)
        ml[(size_t)(ks * 16 + bh) * Q_ + qg] = make_float2(m_run, l_run);
}

// ---------------------------------------------------------------------------
// Merge 3 split-K partials, apply gate, write bf16 [M,512].
// ---------------------------------------------------------------------------
__global__ __launch_bounds__(256)
void merge_kernel(const bf16* __restrict__ po, const float2* __restrict__ ml,
                  const bf16* __restrict__ g, bf16* __restrict__ og)
{
    const int gid = blockIdx.x * 256 + threadIdx.x;
    const int row = gid >> 3;             // bh*2048 + qg
    const int d8  = (gid & 7) * 8;
    const int bh  = row >> 11, qg = row & 2047;
    const int b   = bh >> 3, h = bh & 7;

    float2 m4[3];
    #pragma unroll
    for (int s = 0; s < 3; ++s) m4[s] = ml[(size_t)s * (16 * Q_) + row];
    const float M = fmaxf(fmaxf(m4[0].x, m4[1].x), m4[2].x);
    float w[3], tot = 0.f;
    #pragma unroll
    for (int s = 0; s < 3; ++s) {
        w[s] = m4[s].y * __builtin_amdgcn_exp2f(m4[s].x - M);
        tot += w[s];
    }
    const float inv = 1.f / tot;
    #pragma unroll
    for (int s = 0; s < 3; ++s) w[s] *= inv;

    bf16x8 o[3];
    #pragma unroll
    for (int s = 0; s < 3; ++s)
        o[s] = *(const bf16x8*)(po + (size_t)s * (16 * Q_ * 64) + (size_t)row * 64 + d8);

    const size_t obase = ((size_t)(b * Q_ + qg)) * 512 + h * 64 + d8;
    const bf16x8 gv = *(const bf16x8*)(g + obase);
    bf16x8 ov;
    #pragma unroll
    for (int r = 0; r < 8; ++r) {
        float acc = 0.f;
        #pragma unroll
        for (int s = 0; s < 3; ++s) acc += (float)o[s][r] * w[s];
        ov[r] = (bf16)(acc * (float)gv[r]);
    }
    *(bf16x8*)(og + obase) = ov;
}

// ---------------------------------------------------------------------------
extern "C" void kernel_launch(void* const* d_in, const int* in_sizes, int n_in,
                              void* d_out, int out_size, void* d_ws, size_t ws_size,
                              hipStream_t stream)
{
    const float* q_x   = (const float*)d_in[0];
    const float* bias  = (const float*)d_in[2];
    const float* w_qkv = (const float*)d_in[3];
    const float* w_o   = (const float*)d_in[4];
    const float* b_o   = (const float*)d_in[5];
    const float* w_g   = (const float*)d_in[6];
    const float* b_g   = (const float*)d_in[7];
    float* out = (float*)d_out;

    char* ws = (char*)d_ws;
    bf16*   qxb  = (bf16*)(ws);                    // 4 MB  (dead after gemm0)
    bf16*   wcat = (bf16*)(ws + (4u  << 20));      // 2 MB  (dead after gemm0)
    bf16*   po   = (bf16*)(ws);                    // 12.6 MB partials (overlays qxb/wcat)
    bf16*   qb   = (bf16*)(ws + (16u << 20));      // 4 MB
    bf16*   kb   = (bf16*)(ws + (20u << 20));      // 4 MB  K frag-ordered
    bf16*   vb   = (bf16*)(ws + (24u << 20));      // 4 MB  V^T frag-ordered
    bf16*   gb   = (bf16*)(ws + (28u << 20));      // 4 MB  gate
    bf16*   ogb  = (bf16*)(ws + (32u << 20));      // 4 MB  gated O
    bf16*   wob  = (bf16*)(ws + (36u << 20));      // 0.5 MB
    float2* ml   = (float2*)(ws + (36u << 20) + (1u << 19));  // 0.75 MB -> ends 37.25 MB

    // 1) fp32 -> bf16 conversions
    convert_kernel<<<(S0 + S1 + S2 + S3) / (256 * 8), 256, 0, stream>>>(
        q_x, w_qkv, w_g, w_o, qxb, wcat, wob);
    // 2) fused QKV + gate projection (bf16 MFMA, coalesced epilogue)
    gemm_bf16<128, 128, 0><<<dim3(32, 16), 256, 0, stream>>>(
        qxb, wcat, b_g, nullptr, qb, kb, vb, gb);
    // 3) split-K flash attention partials (3-way split = one full cohort)
    attn_part<<<dim3(B_ * H_, Q_ / 128, 3), 256, 0, stream>>>(qb, kb, vb, bias, po, ml);
    // 4) merge partials + gate
    merge_kernel<<<(16 * Q_ * 8) / 256, 256, 0, stream>>>(po, ml, gb, ogb);
    // 5) output projection + b_o
    gemm_bf16<64, 128, 1><<<dim3(64, 4), 256, 0, stream>>>(
        ogb, wob, b_o, out, nullptr, nullptr, nullptr, nullptr);
}